// Round 3
// baseline (823.240 us; speedup 1.0000x reference)
//
#include <hip/hip_runtime.h>
#include <hip/hip_bf16.h>
#include <stdint.h>

// ---------------------------------------------------------------------------
// HConstructor: slot-attention-like block on MI355X.
//   inputs [65536,256], noise [1024,256] -> edges [1024,256], H [65536,1024],
//   dots2 [65536,1024].
// Pipeline (all on `stream`, scratch carved from dead regions of d_out):
//   prep_w   : Wcat^T = [wk|wv|wq]^T as bf16 [768,256], bias cat
//   edges_e  : edges = mu + exp(ls)*noise ; e = LN(edges)  (f32 + bf16)
//   ln_x     : x = LN(inputs) -> bf16 [65536,256]
//   gemm<1>  : q  = relu(e @ wq + bq)           [1024,256]  bf16
//   gemm<0>  : k,v = relu(x@wk/v + b), q2 = x@wq+bq 768-wide routed epilogue
//   gemm<2>  : dots = (q @ k^T) * 1/16 -> bf16 [1024,65536] (scratch)
//   d2d3     : per row (1024 threads): STREAMING 2-level histogram rank
//              select (high-byte hist -> low-byte hist), row re-read from
//              L2 (3x128KB); softmax stats; fractional tie weighting;
//              sparse attn@v gather.  ~7 barriers, low VGPR.
//   mlp      : edges_out = relu([e,upd]@w1+b1)@w2+b2 -> OUT + bf16
//   gemm<1>  : k2 = relu(edges_out @ wk + bk)   [1024,256]  bf16
//   gemm<3>  : dots2 = (q2 @ k2^T) * 1/16 -> OUT f32
//   g2       : H = softmax(dots2) * top32-mask -> OUT
// ---------------------------------------------------------------------------

#define DEV __device__ __forceinline__

typedef uint32_t u32;
typedef uint16_t u16;
typedef __bf16 v8bf __attribute__((ext_vector_type(8)));
typedef float v4f __attribute__((ext_vector_type(4)));

static constexpr long NN = 65536;
static constexpr long DD = 256;
static constexpr long NSL = 1024;

DEV u16 f2b(float f) {
  u32 u = __builtin_bit_cast(u32, f);
  u32 r = (u + 0x7FFFu + ((u >> 16) & 1u)) >> 16;
  return (u16)r;
}
DEV float b2f(u16 h) { u32 u = ((u32)h) << 16; return __builtin_bit_cast(float, u); }
// bf16 bits (as u32 low16) -> monotone sortable 16-bit key
DEV u32 b2k(u32 b) { return b ^ (0x8000u + 0x7FFFu * (b >> 15)); }
DEV float k2fv(u32 k) {
  u16 b = (k & 0x8000u) ? (u16)(k ^ 0x8000u) : (u16)(k ^ 0xFFFFu);
  return b2f(b);
}

// ---------------------------------------------------------------------------
// Generic  C[M,N] = epilogue(A[M,256] @ B[N,256]^T)   (bf16 in, MFMA 16x16x32)
// 128x128 tile, BK=64, 4 waves (2x2), XOR-swizzled LDS (16B chunk ^ row&7).
// EPI 0: +biascat, relu for cols<512, route cols {0:k,1:v,2:q2} bf16 [M,256]
// EPI 1: +bias, relu, bf16 out [M,256]
// EPI 2: *scale, bf16 out ld=65536
// EPI 3: *scale, f32 out ld=1024
// ---------------------------------------------------------------------------
template <int EPI>
__global__ __launch_bounds__(256, 2)
void gemm_bt(const u16* __restrict__ A, const u16* __restrict__ B,
             const float* __restrict__ bias, float scale,
             u16* __restrict__ ob0, u16* __restrict__ ob1, u16* __restrict__ ob2,
             float* __restrict__ of) {
  __shared__ __align__(16) u16 As[128 * 64];
  __shared__ __align__(16) u16 Bs[128 * 64];
  const int tid = threadIdx.x;
  const int lane = tid & 63;
  const int l15 = lane & 15;
  const int l4 = lane >> 4;
  const int wid = tid >> 6;
  const int wm = wid >> 1, wn = wid & 1;
  const long m0 = (long)blockIdx.y * 128;
  const long n0 = (long)blockIdx.x * 128;

  v4f acc[4][4] = {};

  for (int kb = 0; kb < 256; kb += 64) {
    __syncthreads();
#pragma unroll
    for (int i = 0; i < 4; i++) {
      int cid = tid + 256 * i;          // 1024 16B-chunks per tile
      int row = cid >> 3, ch = cid & 7; // 8 chunks per 64-col row
      int sch = ch ^ (row & 7);
      uint4 da = *reinterpret_cast<const uint4*>(A + (m0 + row) * 256 + kb + ch * 8);
      *reinterpret_cast<uint4*>(&As[row * 64 + sch * 8]) = da;
      uint4 db = *reinterpret_cast<const uint4*>(B + (n0 + row) * 256 + kb + ch * 8);
      *reinterpret_cast<uint4*>(&Bs[row * 64 + sch * 8]) = db;
    }
    __syncthreads();
#pragma unroll
    for (int ks = 0; ks < 2; ks++) {
      v8bf af[4], bfr[4];
#pragma unroll
      for (int m = 0; m < 4; m++) {
        int row = wm * 64 + m * 16 + l15;
        int sch = (ks * 4 + l4) ^ (row & 7);
        af[m] = *reinterpret_cast<const v8bf*>(&As[row * 64 + sch * 8]);
      }
#pragma unroll
      for (int n = 0; n < 4; n++) {
        int row = wn * 64 + n * 16 + l15;
        int sch = (ks * 4 + l4) ^ (row & 7);
        bfr[n] = *reinterpret_cast<const v8bf*>(&Bs[row * 64 + sch * 8]);
      }
#pragma unroll
      for (int m = 0; m < 4; m++)
#pragma unroll
        for (int n = 0; n < 4; n++)
          acc[m][n] = __builtin_amdgcn_mfma_f32_16x16x32_bf16(af[m], bfr[n], acc[m][n], 0, 0, 0);
    }
  }

  const int r4 = l4 * 4;
#pragma unroll
  for (int m = 0; m < 4; m++) {
#pragma unroll
    for (int n = 0; n < 4; n++) {
#pragma unroll
      for (int r = 0; r < 4; r++) {
        long grow = m0 + wm * 64 + m * 16 + r4 + r;
        long gcol = n0 + wn * 64 + n * 16 + l15;
        float v = acc[m][n][r];
        if constexpr (EPI == 0) {
          v += bias[gcol];
          int which = (int)(gcol >> 8);
          long jj = gcol & 255;
          if (which < 2) v = fmaxf(v, 0.f);
          u16 hv = f2b(v);
          if (which == 0) ob0[grow * 256 + jj] = hv;
          else if (which == 1) ob1[grow * 256 + jj] = hv;
          else ob2[grow * 256 + jj] = hv;
        } else if constexpr (EPI == 1) {
          v += bias[gcol];
          v = fmaxf(v, 0.f);
          ob0[grow * 256 + gcol] = f2b(v);
        } else if constexpr (EPI == 2) {
          ob0[grow * 65536 + gcol] = f2b(v * scale);
        } else {
          of[grow * 1024 + gcol] = v * scale;
        }
      }
    }
  }
}

// ---------------------------------------------------------------------------
// Weight prep: Wcat^T bf16 [768,256] rows = [wk cols | wv cols | wq cols]
// ---------------------------------------------------------------------------
__global__ __launch_bounds__(256)
void prep_w_kernel(const float* __restrict__ wq, const float* __restrict__ wk,
                   const float* __restrict__ wv, const float* __restrict__ bq,
                   const float* __restrict__ bk, const float* __restrict__ bv,
                   u16* __restrict__ wcat, float* __restrict__ bcat) {
  int n = blockIdx.x;
  int t = threadIdx.x;
  const float* W = (n < 256) ? wk : (n < 512) ? wv : wq;
  int jj = n & 255;
  wcat[n * 256 + t] = f2b(W[t * 256 + jj]);
  if (t == 0) {
    const float* Bb = (n < 256) ? bk : (n < 512) ? bv : bq;
    bcat[n] = Bb[jj];
  }
}

// ---------------------------------------------------------------------------
// x = LayerNorm(inputs) -> bf16.  One wave per row (4 f32 per lane).
// ---------------------------------------------------------------------------
__global__ __launch_bounds__(256)
void ln_x_kernel(const float* __restrict__ x, const float* __restrict__ lw,
                 const float* __restrict__ lb, u16* __restrict__ out) {
  const int lane = threadIdx.x & 63, wid = threadIdx.x >> 6;
  const long row = (long)blockIdx.x * 4 + wid;
  float4 v = reinterpret_cast<const float4*>(x + row * 256)[lane];
  float s = v.x + v.y + v.z + v.w;
  for (int sh = 1; sh < 64; sh <<= 1) s += __shfl_xor(s, sh);
  float mu = s * (1.f / 256.f);
  float dx = v.x - mu, dy = v.y - mu, dz = v.z - mu, dw = v.w - mu;
  float q = dx * dx + dy * dy + dz * dz + dw * dw;
  for (int sh = 1; sh < 64; sh <<= 1) q += __shfl_xor(q, sh);
  float rs = rsqrtf(q * (1.f / 256.f) + 1e-5f);
  float4 wv = reinterpret_cast<const float4*>(lw)[lane];
  float4 bv = reinterpret_cast<const float4*>(lb)[lane];
  ushort4 o4;
  o4.x = f2b(dx * rs * wv.x + bv.x);
  o4.y = f2b(dy * rs * wv.y + bv.y);
  o4.z = f2b(dz * rs * wv.z + bv.z);
  o4.w = f2b(dw * rs * wv.w + bv.w);
  reinterpret_cast<ushort4*>(out + row * 256)[lane] = o4;
}

// ---------------------------------------------------------------------------
// edges = mu + exp(ls)*noise ; e = LayerNorm(edges) -> f32 + bf16
// ---------------------------------------------------------------------------
__global__ __launch_bounds__(256)
void edges_e_kernel(const float* __restrict__ noise, const float* __restrict__ emu,
                    const float* __restrict__ els, const float* __restrict__ lw,
                    const float* __restrict__ lb, float* __restrict__ e_f,
                    u16* __restrict__ e_b) {
  const int lane = threadIdx.x & 63, wid = threadIdx.x >> 6;
  const long row = (long)blockIdx.x * 4 + wid;
  float4 nz = reinterpret_cast<const float4*>(noise + row * 256)[lane];
  float4 mu4 = reinterpret_cast<const float4*>(emu)[lane];
  float4 ls4 = reinterpret_cast<const float4*>(els)[lane];
  float4 ed;
  ed.x = mu4.x + expf(ls4.x) * nz.x;
  ed.y = mu4.y + expf(ls4.y) * nz.y;
  ed.z = mu4.z + expf(ls4.z) * nz.z;
  ed.w = mu4.w + expf(ls4.w) * nz.w;
  float s = ed.x + ed.y + ed.z + ed.w;
  for (int sh = 1; sh < 64; sh <<= 1) s += __shfl_xor(s, sh);
  float mu = s * (1.f / 256.f);
  float dx = ed.x - mu, dy = ed.y - mu, dz = ed.z - mu, dw = ed.w - mu;
  float qv = dx * dx + dy * dy + dz * dz + dw * dw;
  for (int sh = 1; sh < 64; sh <<= 1) qv += __shfl_xor(qv, sh);
  float rs = rsqrtf(qv * (1.f / 256.f) + 1e-5f);
  float4 wv = reinterpret_cast<const float4*>(lw)[lane];
  float4 bv = reinterpret_cast<const float4*>(lb)[lane];
  float4 ef;
  ef.x = dx * rs * wv.x + bv.x;
  ef.y = dy * rs * wv.y + bv.y;
  ef.z = dz * rs * wv.z + bv.z;
  ef.w = dw * rs * wv.w + bv.w;
  reinterpret_cast<float4*>(e_f + row * 256)[lane] = ef;
  ushort4 o4;
  o4.x = f2b(ef.x); o4.y = f2b(ef.y); o4.z = f2b(ef.z); o4.w = f2b(ef.w);
  reinterpret_cast<ushort4*>(e_b + row * 256)[lane] = o4;
}

// ---------------------------------------------------------------------------
// d2d3: one block (1024 threads) per q-row.  STREAMING version: the row is
// read 3x from L2 (128 KB, XCD-resident), no big register/LDS residency.
// Rank-kn threshold via 2-level byte histogram (per-wave high-byte hist ->
// shared low-byte hist), wave-0 suffix scans.  ~7 barriers total.
// ---------------------------------------------------------------------------
__global__ __launch_bounds__(1024, 8)
void d2d3_kernel(const u16* __restrict__ dots, const u16* __restrict__ vmat,
                 const int* __restrict__ knp, float* __restrict__ upd) {
  __shared__ u32 whist[16][256];   // per-wave high-byte histograms (16 KB)
  __shared__ u32 c_hi[256];
  __shared__ u32 lhist[256];
  __shared__ u32 ured[16];
  __shared__ float fred[16];
  __shared__ u32 sb_star, sThi, sThr;
  __shared__ float sSE, sFrac;
  __shared__ u32 sel_idx[1152];
  __shared__ float sel_w[1152];
  __shared__ float partial[1024];
  __shared__ u32 scnt;

  const int tid = threadIdx.x, lane = tid & 63, wid = tid >> 6;
  const long r = blockIdx.x;
  const int kn = *knp;
  const uint4* src = reinterpret_cast<const uint4*>(dots + r * 65536);

  {
    u32* wh = &whist[0][0];
    for (int i = tid; i < 4096; i += 1024) wh[i] = 0;
  }
  if (tid < 256) lhist[tid] = 0;
  if (tid == 0) scnt = 0;
  __syncthreads();

  // ---- Pass A: block max + per-wave high-byte histogram ----
  u32 kmax = 0;
  u32* myh = &whist[wid][0];
#pragma unroll 2
  for (int i = 0; i < 8; i++) {
    uint4 d = src[tid + 1024 * i];
    u32 k0 = b2k(d.x & 0xffffu), k1 = b2k(d.x >> 16);
    u32 k2 = b2k(d.y & 0xffffu), k3 = b2k(d.y >> 16);
    u32 k4 = b2k(d.z & 0xffffu), k5 = b2k(d.z >> 16);
    u32 k6 = b2k(d.w & 0xffffu), k7 = b2k(d.w >> 16);
    atomicAdd(&myh[k0 >> 8], 1u); atomicAdd(&myh[k1 >> 8], 1u);
    atomicAdd(&myh[k2 >> 8], 1u); atomicAdd(&myh[k3 >> 8], 1u);
    atomicAdd(&myh[k4 >> 8], 1u); atomicAdd(&myh[k5 >> 8], 1u);
    atomicAdd(&myh[k6 >> 8], 1u); atomicAdd(&myh[k7 >> 8], 1u);
    u32 a = k0 > k1 ? k0 : k1, b = k2 > k3 ? k2 : k3;
    u32 c = k4 > k5 ? k4 : k5, e = k6 > k7 ? k6 : k7;
    a = a > b ? a : b; c = c > e ? c : e; a = a > c ? a : c;
    kmax = kmax > a ? kmax : a;
  }
  for (int sh = 1; sh < 64; sh <<= 1) {
    u32 t = (u32)__shfl_xor((int)kmax, sh);
    kmax = kmax > t ? kmax : t;
  }
  if (lane == 0) ured[wid] = kmax;
  __syncthreads();

  // reduce per-wave hists -> c_hi
  if (tid < 256) {
    u32 s = 0;
#pragma unroll
    for (int w = 0; w < 16; w++) s += whist[w][tid];
    c_hi[tid] = s;
  }
  __syncthreads();

  // wave 0: suffix scan (from bin 255 down) to find high byte b*
  if (tid < 64) {
    u32 s = c_hi[4 * tid] + c_hi[4 * tid + 1] + c_hi[4 * tid + 2] + c_hi[4 * tid + 3];
    u32 v = s;
    for (int off = 1; off < 64; off <<= 1) {
      u32 t = (u32)__shfl_down((int)v, off);
      if (tid + off < 64) v += t;        // inclusive suffix sum over lanes
    }
    u32 excl = v - s;                    // count in bins above this lane's range
    if (v >= (u32)kn && excl < (u32)kn) {
      u32 acc = excl;
#pragma unroll
      for (int bb = 3; bb >= 0; --bb) {
        int b = 4 * tid + bb;
        u32 nb = acc + c_hi[b];
        if (nb >= (u32)kn) { sb_star = (u32)b; sThi = acc; break; }
        acc = nb;
      }
    }
  }
  __syncthreads();
  const u32 bstar = sb_star;
  u32 gk = ured[0];
#pragma unroll
  for (int i = 1; i < 16; i++) gk = gk > ured[i] ? gk : ured[i];
  const float M = k2fv(gk);

  // ---- Pass B: sum-exp + low-byte histogram within bin b* ----
  float se = 0.f;
#pragma unroll 2
  for (int i = 0; i < 8; i++) {
    uint4 d = src[tid + 1024 * i];
    u32 kk0 = b2k(d.x & 0xffffu), kk1 = b2k(d.x >> 16);
    u32 kk2 = b2k(d.y & 0xffffu), kk3 = b2k(d.y >> 16);
    u32 kk4 = b2k(d.z & 0xffffu), kk5 = b2k(d.z >> 16);
    u32 kk6 = b2k(d.w & 0xffffu), kk7 = b2k(d.w >> 16);
    se += expf(k2fv(kk0) - M) + expf(k2fv(kk1) - M)
        + expf(k2fv(kk2) - M) + expf(k2fv(kk3) - M)
        + expf(k2fv(kk4) - M) + expf(k2fv(kk5) - M)
        + expf(k2fv(kk6) - M) + expf(k2fv(kk7) - M);
    if ((kk0 >> 8) == bstar) atomicAdd(&lhist[kk0 & 255u], 1u);
    if ((kk1 >> 8) == bstar) atomicAdd(&lhist[kk1 & 255u], 1u);
    if ((kk2 >> 8) == bstar) atomicAdd(&lhist[kk2 & 255u], 1u);
    if ((kk3 >> 8) == bstar) atomicAdd(&lhist[kk3 & 255u], 1u);
    if ((kk4 >> 8) == bstar) atomicAdd(&lhist[kk4 & 255u], 1u);
    if ((kk5 >> 8) == bstar) atomicAdd(&lhist[kk5 & 255u], 1u);
    if ((kk6 >> 8) == bstar) atomicAdd(&lhist[kk6 & 255u], 1u);
    if ((kk7 >> 8) == bstar) atomicAdd(&lhist[kk7 & 255u], 1u);
  }
  for (int sh = 1; sh < 64; sh <<= 1) se += __shfl_xor(se, sh);
  if (lane == 0) fred[wid] = se;
  __syncthreads();

  // wave 0: low-byte suffix scan -> exact threshold + tie counts
  if (tid < 64) {
    u32 s = lhist[4 * tid] + lhist[4 * tid + 1] + lhist[4 * tid + 2] + lhist[4 * tid + 3];
    u32 v = s;
    for (int off = 1; off < 64; off <<= 1) {
      u32 t = (u32)__shfl_down((int)v, off);
      if (tid + off < 64) v += t;
    }
    const u32 Thi = sThi;                // count(high byte > b*)
    u32 incl = v + Thi;
    u32 excl = v - s + Thi;
    if (incl >= (u32)kn && excl < (u32)kn) {
      u32 acc = excl;
#pragma unroll
      for (int bb = 3; bb >= 0; --bb) {
        int b = 4 * tid + bb;
        u32 nb = acc + lhist[b];
        if (nb >= (u32)kn) {
          sThr = (bstar << 8) | (u32)b;
          // acc = count(key > thr), lhist[b] = count(key == thr)
          sFrac = (float)(int)((u32)kn - acc) / (float)lhist[b];
          break;
        }
        acc = nb;
      }
    }
    if (tid == 0) {
      float SE = 0.f;
#pragma unroll
      for (int i = 0; i < 16; i++) SE += fred[i];
      sSE = SE;
    }
  }
  __syncthreads();
  const u32 thr = sThr;
  const float frac = sFrac;
  const float invs = 1.f / sSE;
  const float wnorm = 1.f / (1.f + 65536.f * 1e-8f);

  // ---- Pass C: selection: keys >= thr -> (global idx, weight) list ----
#pragma unroll 2
  for (int i = 0; i < 8; i++) {
    const int c = tid + 1024 * i;
    uint4 d = src[c];
    u32 kk[8] = {b2k(d.x & 0xffffu), b2k(d.x >> 16), b2k(d.y & 0xffffu), b2k(d.y >> 16),
                 b2k(d.z & 0xffffu), b2k(d.z >> 16), b2k(d.w & 0xffffu), b2k(d.w >> 16)};
#pragma unroll
    for (int q = 0; q < 8; q++) {
      if (kk[q] >= thr) {
        float w = (expf(k2fv(kk[q]) - M) * invs + 1e-8f) * wnorm;
        if (kk[q] == thr) w *= frac;
        u32 p = atomicAdd(&scnt, 1u);
        if (p < 1152u) { sel_idx[p] = (u32)c * 8u + (u32)q; sel_w[p] = w; }
      }
    }
  }
  __syncthreads();
  const u32 nsel = scnt < 1152u ? scnt : 1152u;

  // ---- Pass D: sparse accumulate: 4 groups x 256 cols, then combine ----
  const int g = tid >> 8, col = tid & 255;
  float a0 = 0.f, a1 = 0.f;
  u32 j = (u32)g;
  for (; j + 4 < nsel; j += 8) {
    a0 = fmaf(sel_w[j], b2f(vmat[(long)sel_idx[j] * 256 + col]), a0);
    a1 = fmaf(sel_w[j + 4], b2f(vmat[(long)sel_idx[j + 4] * 256 + col]), a1);
  }
  if (j < nsel)
    a0 = fmaf(sel_w[j], b2f(vmat[(long)sel_idx[j] * 256 + col]), a0);
  partial[tid] = a0 + a1;
  __syncthreads();
  if (tid < 256)
    upd[r * 256 + tid] = partial[tid] + partial[256 + tid] + partial[512 + tid] + partial[768 + tid];
}

// ---------------------------------------------------------------------------
// mlp: edges_out = relu([e, upd] @ w1 + b1) @ w2 + b2   (f32, one block/row)
// ---------------------------------------------------------------------------
__global__ __launch_bounds__(256)
void mlp_kernel(const float* __restrict__ e, const float* __restrict__ upd,
                const float* __restrict__ w1, const float* __restrict__ b1,
                const float* __restrict__ w2, const float* __restrict__ b2,
                float* __restrict__ eout, u16* __restrict__ eb) {
  __shared__ float ecat[512];
  __shared__ float h[256];
  const int t = threadIdx.x;
  const long r = blockIdx.x;
  ecat[t] = e[r * 256 + t];
  ecat[256 + t] = upd[r * 256 + t];
  __syncthreads();
  float acc = b1[t];
#pragma unroll 8
  for (int kk = 0; kk < 512; ++kk) acc = fmaf(ecat[kk], w1[kk * 256 + t], acc);
  h[t] = fmaxf(acc, 0.f);
  __syncthreads();
  float a2 = b2[t];
#pragma unroll 8
  for (int kk = 0; kk < 256; ++kk) a2 = fmaf(h[kk], w2[kk * 256 + t], a2);
  eout[r * 256 + t] = a2;
  eb[r * 256 + t] = f2b(a2);
}

// ---------------------------------------------------------------------------
// g2: per row of dots2 [65536,1024]: softmax, top-ke mask, write H.
// One wave per row, 16 f32/lane, 32-step binary search on f32 monotone key.
// ---------------------------------------------------------------------------
__global__ __launch_bounds__(256)
void g2_kernel(const float* __restrict__ d2, const int* __restrict__ kep,
               float* __restrict__ H) {
  const int lane = threadIdx.x & 63, wid = threadIdx.x >> 6;
  const long row = (long)blockIdx.x * 4 + wid;
  const int ke = *kep;
  const float4* src = reinterpret_cast<const float4*>(d2 + row * 1024);
  float4 q0 = src[lane], q1 = src[64 + lane], q2v = src[128 + lane], q3 = src[192 + lane];
  float x[16] = {q0.x, q0.y, q0.z, q0.w, q1.x, q1.y, q1.z, q1.w,
                 q2v.x, q2v.y, q2v.z, q2v.w, q3.x, q3.y, q3.z, q3.w};
  float mx = x[0];
#pragma unroll
  for (int i = 1; i < 16; i++) mx = fmaxf(mx, x[i]);
  for (int sh = 1; sh < 64; sh <<= 1) mx = fmaxf(mx, __shfl_xor(mx, sh));
  float p[16];
  float se = 0.f;
#pragma unroll
  for (int i = 0; i < 16; i++) { p[i] = expf(x[i] - mx); se += p[i]; }
  for (int sh = 1; sh < 64; sh <<= 1) se += __shfl_xor(se, sh);
  const float invs = 1.f / se;
  u32 key[16];
#pragma unroll
  for (int i = 0; i < 16; i++) {
    u32 u = __builtin_bit_cast(u32, x[i]);
    key[i] = u ^ ((u >> 31) ? 0xFFFFFFFFu : 0x80000000u);
  }
  u32 lo = 0;
  for (int b = 31; b >= 0; --b) {
    u32 t = lo | (1u << b);
    int cnt = 0;
#pragma unroll
    for (int i = 0; i < 16; i++) cnt += (key[i] >= t);
    for (int sh = 1; sh < 64; sh <<= 1) cnt += __shfl_xor(cnt, sh);
    if (cnt >= ke) lo = t;
  }
  float4 o0, o1, o2, o3;
  o0.x = key[0] >= lo ? p[0] * invs : 0.f;
  o0.y = key[1] >= lo ? p[1] * invs : 0.f;
  o0.z = key[2] >= lo ? p[2] * invs : 0.f;
  o0.w = key[3] >= lo ? p[3] * invs : 0.f;
  o1.x = key[4] >= lo ? p[4] * invs : 0.f;
  o1.y = key[5] >= lo ? p[5] * invs : 0.f;
  o1.z = key[6] >= lo ? p[6] * invs : 0.f;
  o1.w = key[7] >= lo ? p[7] * invs : 0.f;
  o2.x = key[8] >= lo ? p[8] * invs : 0.f;
  o2.y = key[9] >= lo ? p[9] * invs : 0.f;
  o2.z = key[10] >= lo ? p[10] * invs : 0.f;
  o2.w = key[11] >= lo ? p[11] * invs : 0.f;
  o3.x = key[12] >= lo ? p[12] * invs : 0.f;
  o3.y = key[13] >= lo ? p[13] * invs : 0.f;
  o3.z = key[14] >= lo ? p[14] * invs : 0.f;
  o3.w = key[15] >= lo ? p[15] * invs : 0.f;
  float4* dst = reinterpret_cast<float4*>(H + row * 1024);
  dst[lane] = o0;
  dst[64 + lane] = o1;
  dst[128 + lane] = o2;
  dst[192 + lane] = o3;
}

// ---------------------------------------------------------------------------
extern "C" void kernel_launch(void* const* d_in, const int* in_sizes, int n_in,
                              void* d_out, int out_size, void* d_ws, size_t ws_size,
                              hipStream_t stream) {
  (void)in_sizes; (void)n_in; (void)out_size; (void)d_ws; (void)ws_size;

  float* out = (float*)d_out;
  float* out_edges = out;                       // [1024,256]
  float* out_H = out + NSL * DD;                // [65536,1024]
  float* out_d2 = out_H + NN * NSL;             // [65536,1024]

  // scratch carved from d_out (regions are dead until their writer runs):
  // H region: dots bf16 (134MB) + q2 bf16 (32MB) + small block; overwritten by g2 last.
  char* Hb = (char*)out_H;
  u16* dots = (u16*)Hb;                          // 1024*65536*2
  u16* q2b = (u16*)(Hb + 134217728L);            // 65536*256*2
  char* smb = Hb + 167772160L;
  u16* wcat = (u16*)smb;      smb += 768 * 256 * 2;
  float* bcat = (float*)smb;  smb += 768 * 4;
  float* e_f = (float*)smb;   smb += 1024 * 256 * 4;
  u16* e_b = (u16*)smb;       smb += 1024 * 256 * 2;
  u16* q_b = (u16*)smb;       smb += 1024 * 256 * 2;
  float* updf = (float*)smb;  smb += 1024 * 256 * 4;
  u16* edg_b = (u16*)smb;     smb += 1024 * 256 * 2;
  u16* k2_b = (u16*)smb;      smb += 1024 * 256 * 2;
  // dots2 region: x_ln, k, v bf16 (32MB each); overwritten by gemm<3>.
  char* Db = (char*)out_d2;
  u16* xln = (u16*)Db;
  u16* kb_ = (u16*)(Db + 33554432L);
  u16* vb_ = (u16*)(Db + 67108864L);

  prep_w_kernel<<<768, 256, 0, stream>>>(
      (const float*)d_in[4], (const float*)d_in[6], (const float*)d_in[8],
      (const float*)d_in[5], (const float*)d_in[7], (const float*)d_in[9], wcat, bcat);
  edges_e_kernel<<<256, 256, 0, stream>>>(
      (const float*)d_in[1], (const float*)d_in[2], (const float*)d_in[3],
      (const float*)d_in[16], (const float*)d_in[17], e_f, e_b);
  ln_x_kernel<<<16384, 256, 0, stream>>>(
      (const float*)d_in[0], (const float*)d_in[14], (const float*)d_in[15], xln);
  gemm_bt<1><<<dim3(2, 8), 256, 0, stream>>>(e_b, wcat + 512 * 256, bcat + 512, 1.f,
                                             q_b, nullptr, nullptr, nullptr);
  gemm_bt<0><<<dim3(6, 512), 256, 0, stream>>>(xln, wcat, bcat, 1.f,
                                               kb_, vb_, q2b, nullptr);
  gemm_bt<2><<<dim3(512, 8), 256, 0, stream>>>(q_b, kb_, nullptr, 0.0625f,
                                               dots, nullptr, nullptr, nullptr);
  d2d3_kernel<<<1024, 1024, 0, stream>>>(dots, vb_, (const int*)d_in[18], updf);
  mlp_kernel<<<1024, 256, 0, stream>>>(e_f, updf,
                                       (const float*)d_in[10], (const float*)d_in[11],
                                       (const float*)d_in[12], (const float*)d_in[13],
                                       out_edges, edg_b);
  gemm_bt<1><<<dim3(2, 8), 256, 0, stream>>>(edg_b, wcat, bcat, 1.f,
                                             k2_b, nullptr, nullptr, nullptr);
  gemm_bt<3><<<dim3(8, 512), 256, 0, stream>>>(q2b, k2_b, nullptr, 0.0625f,
                                               nullptr, nullptr, nullptr, out_d2);
  g2_kernel<<<16384, 256, 0, stream>>>(out_d2, (const int*)d_in[19], out_H);
}

// Round 4
// 777.905 us; speedup vs baseline: 1.0583x; 1.0583x over previous
//
#include <hip/hip_runtime.h>
#include <hip/hip_bf16.h>
#include <stdint.h>

// ---------------------------------------------------------------------------
// HConstructor: slot-attention-like block on MI355X.
//   inputs [65536,256], noise [1024,256] -> edges [1024,256], H [65536,1024],
//   dots2 [65536,1024].
// Pipeline (all on `stream`, scratch carved from dead regions of d_out):
//   prep_w   : Wcat^T = [wk|wv|wq]^T as bf16 [768,256], bias cat
//   edges_e  : edges = mu + exp(ls)*noise ; e = LN(edges)  (f32 + bf16)
//   ln_x     : x = LN(inputs) -> bf16 [65536,256]
//   gemm<1>  : q  = relu(e @ wq + bq)           [1024,256]  bf16
//   gemm<0>  : k,v = relu(x@wk/v + b), q2 = x@wq+bq 768-wide routed epilogue
//   gemm<2>  : dots = (q @ k^T) * 1/16 -> bf16 [1024,65536] (scratch)
//   d2d3     : per row (1024 thr, 1 blk/CU, NO SPILL): row in REGISTERS
//              (32 packed u32 = 64 bf16 keys/thread, 128-VGPR budget via
//              __launch_bounds__(1024,4)); max/sum-exp/16-step rank search/
//              selection all from registers; sparse attn@v gather.
//   mlp      : edges_out = relu([e,upd]@w1+b1)@w2+b2 -> OUT + bf16
//   gemm<1>  : k2 = relu(edges_out @ wk + bk)   [1024,256]  bf16
//   gemm<3>  : dots2 = (q2 @ k2^T) * 1/16 -> OUT f32
//   g2       : H = softmax(dots2) * top32-mask -> OUT
// ---------------------------------------------------------------------------

#define DEV __device__ __forceinline__

typedef uint32_t u32;
typedef uint16_t u16;
typedef __bf16 v8bf __attribute__((ext_vector_type(8)));
typedef float v4f __attribute__((ext_vector_type(4)));

static constexpr long NN = 65536;
static constexpr long DD = 256;
static constexpr long NSL = 1024;

DEV u16 f2b(float f) {
  u32 u = __builtin_bit_cast(u32, f);
  u32 r = (u + 0x7FFFu + ((u >> 16) & 1u)) >> 16;
  return (u16)r;
}
DEV float b2f(u16 h) { u32 u = ((u32)h) << 16; return __builtin_bit_cast(float, u); }
// bf16 bits (as u32 low16) -> monotone sortable 16-bit key
DEV u32 b2k(u32 b) { return b ^ (0x8000u + 0x7FFFu * (b >> 15)); }
DEV float k2fv(u32 k) {
  u16 b = (k & 0x8000u) ? (u16)(k ^ 0x8000u) : (u16)(k ^ 0xFFFFu);
  return b2f(b);
}

// ---------------------------------------------------------------------------
// Generic  C[M,N] = epilogue(A[M,256] @ B[N,256]^T)   (bf16 in, MFMA 16x16x32)
// 128x128 tile, BK=64, 4 waves (2x2), XOR-swizzled LDS (16B chunk ^ row&7).
// EPI 0: +biascat, relu for cols<512, route cols {0:k,1:v,2:q2} bf16 [M,256]
// EPI 1: +bias, relu, bf16 out [M,256]
// EPI 2: *scale, bf16 out ld=65536
// EPI 3: *scale, f32 out ld=1024
// ---------------------------------------------------------------------------
template <int EPI>
__global__ __launch_bounds__(256, 2)
void gemm_bt(const u16* __restrict__ A, const u16* __restrict__ B,
             const float* __restrict__ bias, float scale,
             u16* __restrict__ ob0, u16* __restrict__ ob1, u16* __restrict__ ob2,
             float* __restrict__ of) {
  __shared__ __align__(16) u16 As[128 * 64];
  __shared__ __align__(16) u16 Bs[128 * 64];
  const int tid = threadIdx.x;
  const int lane = tid & 63;
  const int l15 = lane & 15;
  const int l4 = lane >> 4;
  const int wid = tid >> 6;
  const int wm = wid >> 1, wn = wid & 1;
  const long m0 = (long)blockIdx.y * 128;
  const long n0 = (long)blockIdx.x * 128;

  v4f acc[4][4] = {};

  for (int kb = 0; kb < 256; kb += 64) {
    __syncthreads();
#pragma unroll
    for (int i = 0; i < 4; i++) {
      int cid = tid + 256 * i;          // 1024 16B-chunks per tile
      int row = cid >> 3, ch = cid & 7; // 8 chunks per 64-col row
      int sch = ch ^ (row & 7);
      uint4 da = *reinterpret_cast<const uint4*>(A + (m0 + row) * 256 + kb + ch * 8);
      *reinterpret_cast<uint4*>(&As[row * 64 + sch * 8]) = da;
      uint4 db = *reinterpret_cast<const uint4*>(B + (n0 + row) * 256 + kb + ch * 8);
      *reinterpret_cast<uint4*>(&Bs[row * 64 + sch * 8]) = db;
    }
    __syncthreads();
#pragma unroll
    for (int ks = 0; ks < 2; ks++) {
      v8bf af[4], bfr[4];
#pragma unroll
      for (int m = 0; m < 4; m++) {
        int row = wm * 64 + m * 16 + l15;
        int sch = (ks * 4 + l4) ^ (row & 7);
        af[m] = *reinterpret_cast<const v8bf*>(&As[row * 64 + sch * 8]);
      }
#pragma unroll
      for (int n = 0; n < 4; n++) {
        int row = wn * 64 + n * 16 + l15;
        int sch = (ks * 4 + l4) ^ (row & 7);
        bfr[n] = *reinterpret_cast<const v8bf*>(&Bs[row * 64 + sch * 8]);
      }
#pragma unroll
      for (int m = 0; m < 4; m++)
#pragma unroll
        for (int n = 0; n < 4; n++)
          acc[m][n] = __builtin_amdgcn_mfma_f32_16x16x32_bf16(af[m], bfr[n], acc[m][n], 0, 0, 0);
    }
  }

  const int r4 = l4 * 4;
#pragma unroll
  for (int m = 0; m < 4; m++) {
#pragma unroll
    for (int n = 0; n < 4; n++) {
#pragma unroll
      for (int r = 0; r < 4; r++) {
        long grow = m0 + wm * 64 + m * 16 + r4 + r;
        long gcol = n0 + wn * 64 + n * 16 + l15;
        float v = acc[m][n][r];
        if constexpr (EPI == 0) {
          v += bias[gcol];
          int which = (int)(gcol >> 8);
          long jj = gcol & 255;
          if (which < 2) v = fmaxf(v, 0.f);
          u16 hv = f2b(v);
          if (which == 0) ob0[grow * 256 + jj] = hv;
          else if (which == 1) ob1[grow * 256 + jj] = hv;
          else ob2[grow * 256 + jj] = hv;
        } else if constexpr (EPI == 1) {
          v += bias[gcol];
          v = fmaxf(v, 0.f);
          ob0[grow * 256 + gcol] = f2b(v);
        } else if constexpr (EPI == 2) {
          ob0[grow * 65536 + gcol] = f2b(v * scale);
        } else {
          of[grow * 1024 + gcol] = v * scale;
        }
      }
    }
  }
}

// ---------------------------------------------------------------------------
// Weight prep: Wcat^T bf16 [768,256] rows = [wk cols | wv cols | wq cols]
// ---------------------------------------------------------------------------
__global__ __launch_bounds__(256)
void prep_w_kernel(const float* __restrict__ wq, const float* __restrict__ wk,
                   const float* __restrict__ wv, const float* __restrict__ bq,
                   const float* __restrict__ bk, const float* __restrict__ bv,
                   u16* __restrict__ wcat, float* __restrict__ bcat) {
  int n = blockIdx.x;
  int t = threadIdx.x;
  const float* W = (n < 256) ? wk : (n < 512) ? wv : wq;
  int jj = n & 255;
  wcat[n * 256 + t] = f2b(W[t * 256 + jj]);
  if (t == 0) {
    const float* Bb = (n < 256) ? bk : (n < 512) ? bv : bq;
    bcat[n] = Bb[jj];
  }
}

// ---------------------------------------------------------------------------
// x = LayerNorm(inputs) -> bf16.  One wave per row (4 f32 per lane).
// ---------------------------------------------------------------------------
__global__ __launch_bounds__(256)
void ln_x_kernel(const float* __restrict__ x, const float* __restrict__ lw,
                 const float* __restrict__ lb, u16* __restrict__ out) {
  const int lane = threadIdx.x & 63, wid = threadIdx.x >> 6;
  const long row = (long)blockIdx.x * 4 + wid;
  float4 v = reinterpret_cast<const float4*>(x + row * 256)[lane];
  float s = v.x + v.y + v.z + v.w;
  for (int sh = 1; sh < 64; sh <<= 1) s += __shfl_xor(s, sh);
  float mu = s * (1.f / 256.f);
  float dx = v.x - mu, dy = v.y - mu, dz = v.z - mu, dw = v.w - mu;
  float q = dx * dx + dy * dy + dz * dz + dw * dw;
  for (int sh = 1; sh < 64; sh <<= 1) q += __shfl_xor(q, sh);
  float rs = rsqrtf(q * (1.f / 256.f) + 1e-5f);
  float4 wv = reinterpret_cast<const float4*>(lw)[lane];
  float4 bv = reinterpret_cast<const float4*>(lb)[lane];
  ushort4 o4;
  o4.x = f2b(dx * rs * wv.x + bv.x);
  o4.y = f2b(dy * rs * wv.y + bv.y);
  o4.z = f2b(dz * rs * wv.z + bv.z);
  o4.w = f2b(dw * rs * wv.w + bv.w);
  reinterpret_cast<ushort4*>(out + row * 256)[lane] = o4;
}

// ---------------------------------------------------------------------------
// edges = mu + exp(ls)*noise ; e = LayerNorm(edges) -> f32 + bf16
// ---------------------------------------------------------------------------
__global__ __launch_bounds__(256)
void edges_e_kernel(const float* __restrict__ noise, const float* __restrict__ emu,
                    const float* __restrict__ els, const float* __restrict__ lw,
                    const float* __restrict__ lb, float* __restrict__ e_f,
                    u16* __restrict__ e_b) {
  const int lane = threadIdx.x & 63, wid = threadIdx.x >> 6;
  const long row = (long)blockIdx.x * 4 + wid;
  float4 nz = reinterpret_cast<const float4*>(noise + row * 256)[lane];
  float4 mu4 = reinterpret_cast<const float4*>(emu)[lane];
  float4 ls4 = reinterpret_cast<const float4*>(els)[lane];
  float4 ed;
  ed.x = mu4.x + expf(ls4.x) * nz.x;
  ed.y = mu4.y + expf(ls4.y) * nz.y;
  ed.z = mu4.z + expf(ls4.z) * nz.z;
  ed.w = mu4.w + expf(ls4.w) * nz.w;
  float s = ed.x + ed.y + ed.z + ed.w;
  for (int sh = 1; sh < 64; sh <<= 1) s += __shfl_xor(s, sh);
  float mu = s * (1.f / 256.f);
  float dx = ed.x - mu, dy = ed.y - mu, dz = ed.z - mu, dw = ed.w - mu;
  float qv = dx * dx + dy * dy + dz * dz + dw * dw;
  for (int sh = 1; sh < 64; sh <<= 1) qv += __shfl_xor(qv, sh);
  float rs = rsqrtf(qv * (1.f / 256.f) + 1e-5f);
  float4 wv = reinterpret_cast<const float4*>(lw)[lane];
  float4 bv = reinterpret_cast<const float4*>(lb)[lane];
  float4 ef;
  ef.x = dx * rs * wv.x + bv.x;
  ef.y = dy * rs * wv.y + bv.y;
  ef.z = dz * rs * wv.z + bv.z;
  ef.w = dw * rs * wv.w + bv.w;
  reinterpret_cast<float4*>(e_f + row * 256)[lane] = ef;
  ushort4 o4;
  o4.x = f2b(ef.x); o4.y = f2b(ef.y); o4.z = f2b(ef.z); o4.w = f2b(ef.w);
  reinterpret_cast<ushort4*>(e_b + row * 256)[lane] = o4;
}

// ---------------------------------------------------------------------------
// d2d3: one block (1024 threads = 16 waves, 1 block/CU) per q-row.
// Row read ONCE from global into registers: kv[32] packed u32 = 64 bf16
// monotone keys per thread.  __launch_bounds__(1024,4) -> 128 VGPR cap so
// kv stays in registers (round-2 variant spilled at the default 64-cap).
// max / sum-exp / 16-step rank-kn binary search / tie counts / selection
// all operate on registers; one barrier per search step.
// ---------------------------------------------------------------------------
__global__ __launch_bounds__(1024, 4)
void d2d3_kernel(const u16* __restrict__ dots, const u16* __restrict__ vmat,
                 const int* __restrict__ knp, float* __restrict__ upd) {
  __shared__ u32 ured[2][16];
  __shared__ u32 uredG[16];
  __shared__ u32 uredE[16];
  __shared__ u32 umax[16];
  __shared__ float fred[16];
  __shared__ u32 sel_idx[1152];
  __shared__ float sel_w[1152];
  __shared__ float partial[1024];
  __shared__ u32 scnt;

  const int tid = threadIdx.x, lane = tid & 63, wid = tid >> 6;
  const long r = blockIdx.x;
  const int kn = *knp;
  if (tid == 0) scnt = 0;

  // ---- single global read: row -> packed monotone keys in registers ----
  const uint4* src = reinterpret_cast<const uint4*>(dots + r * 65536);
  u32 kv[32];
  u32 kmax = 0;
#pragma unroll
  for (int i = 0; i < 8; i++) {
    uint4 d = src[tid + 1024 * i];
    u32 w0 = b2k(d.x & 0xffffu) | (b2k(d.x >> 16) << 16);
    u32 w1 = b2k(d.y & 0xffffu) | (b2k(d.y >> 16) << 16);
    u32 w2 = b2k(d.z & 0xffffu) | (b2k(d.z >> 16) << 16);
    u32 w3 = b2k(d.w & 0xffffu) | (b2k(d.w >> 16) << 16);
    kv[i * 4 + 0] = w0; kv[i * 4 + 1] = w1; kv[i * 4 + 2] = w2; kv[i * 4 + 3] = w3;
    u32 m0 = (w0 & 0xffffu) > (w0 >> 16) ? (w0 & 0xffffu) : (w0 >> 16);
    u32 m1 = (w1 & 0xffffu) > (w1 >> 16) ? (w1 & 0xffffu) : (w1 >> 16);
    u32 m2 = (w2 & 0xffffu) > (w2 >> 16) ? (w2 & 0xffffu) : (w2 >> 16);
    u32 m3 = (w3 & 0xffffu) > (w3 >> 16) ? (w3 & 0xffffu) : (w3 >> 16);
    u32 ma = m0 > m1 ? m0 : m1;
    u32 mb = m2 > m3 ? m2 : m3;
    u32 mc = ma > mb ? ma : mb;
    kmax = kmax > mc ? kmax : mc;
  }
  for (int sh = 1; sh < 64; sh <<= 1) {
    u32 t = (u32)__shfl_xor((int)kmax, sh);
    kmax = kmax > t ? kmax : t;
  }
  if (lane == 0) umax[wid] = kmax;
  __syncthreads();
  u32 gk = umax[0];
#pragma unroll
  for (int i = 1; i < 16; i++) gk = gk > umax[i] ? gk : umax[i];
  const float M = k2fv(gk);

  // ---- sum of exp (registers only); fred visible after next barrier ----
  float se = 0.f;
#pragma unroll
  for (int i = 0; i < 32; i++)
    se += expf(k2fv(kv[i] & 0xffffu) - M) + expf(k2fv(kv[i] >> 16) - M);
  for (int sh = 1; sh < 64; sh <<= 1) se += __shfl_xor(se, sh);
  if (lane == 0) fred[wid] = se;

  // ---- 16-step binary search for rank-kn threshold (1 barrier/step) ----
  u32 lo = 0;
  for (int b = 15; b >= 0; --b) {
    const u32 t = lo | (1u << b);
    const u32 th = t << 16;
    u32 c = 0;
#pragma unroll
    for (int i = 0; i < 32; i++)
      c += (u32)((kv[i] & 0xffffu) >= t) + (u32)(kv[i] >= th);
    for (int sh = 1; sh < 64; sh <<= 1) c += (u32)__shfl_xor((int)c, sh);
    if (lane == 0) ured[b & 1][wid] = c;
    __syncthreads();
    u32 tot = 0;
#pragma unroll
    for (int i = 0; i < 16; i++) tot += ured[b & 1][i];
    if (tot >= (u32)kn) lo = t;
  }
  const u32 thr = lo;

  // ---- counts >thr and ==thr for fractional tie weighting ----
  const u32 thrh = thr << 16;
  u32 cg = 0, ce = 0;
#pragma unroll
  for (int i = 0; i < 32; i++) {
    u32 kl = kv[i] & 0xffffu, kh = kv[i] >> 16;
    cg += (u32)(kl > thr) + (u32)(kv[i] > (thrh | 0xffffu));
    ce += (u32)(kl == thr) + (u32)(kh == thr);
  }
  for (int sh = 1; sh < 64; sh <<= 1) {
    cg += (u32)__shfl_xor((int)cg, sh);
    ce += (u32)__shfl_xor((int)ce, sh);
  }
  if (lane == 0) { uredG[wid] = cg; uredE[wid] = ce; }
  __syncthreads();
  u32 CG = 0, CE = 0;
#pragma unroll
  for (int i = 0; i < 16; i++) { CG += uredG[i]; CE += uredE[i]; }
  const float frac = (float)(int)((u32)kn - CG) / (float)CE;
  float SE = 0.f;
#pragma unroll
  for (int i = 0; i < 16; i++) SE += fred[i];

  const float invs = 1.f / SE;
  const float wnorm = 1.f / (1.f + 65536.f * 1e-8f);

  // ---- selection: keys >= thr -> (global idx, weight) list ----
#pragma unroll
  for (int i = 0; i < 32; i++) {
    const u32 base = (u32)(tid + 1024 * (i >> 2)) * 8 + (u32)(i & 3) * 2;
    u32 kl = kv[i] & 0xffffu;
    if (kl >= thr) {
      float w = (expf(k2fv(kl) - M) * invs + 1e-8f) * wnorm;
      if (kl == thr) w *= frac;
      u32 p = atomicAdd(&scnt, 1u);
      if (p < 1152u) { sel_idx[p] = base; sel_w[p] = w; }
    }
    u32 kh = kv[i] >> 16;
    if (kh >= thr) {
      float w = (expf(k2fv(kh) - M) * invs + 1e-8f) * wnorm;
      if (kh == thr) w *= frac;
      u32 p = atomicAdd(&scnt, 1u);
      if (p < 1152u) { sel_idx[p] = base + 1; sel_w[p] = w; }
    }
  }
  __syncthreads();
  const u32 nsel = scnt < 1152u ? scnt : 1152u;

  // ---- sparse accumulate: 4 groups x 256 cols, 4-deep ILP, combine ----
  const int g = tid >> 8, col = tid & 255;
  float a0 = 0.f, a1 = 0.f, a2 = 0.f, a3 = 0.f;
  u32 j = (u32)g;
  for (; j + 12 < nsel; j += 16) {
    a0 = fmaf(sel_w[j], b2f(vmat[(long)sel_idx[j] * 256 + col]), a0);
    a1 = fmaf(sel_w[j + 4], b2f(vmat[(long)sel_idx[j + 4] * 256 + col]), a1);
    a2 = fmaf(sel_w[j + 8], b2f(vmat[(long)sel_idx[j + 8] * 256 + col]), a2);
    a3 = fmaf(sel_w[j + 12], b2f(vmat[(long)sel_idx[j + 12] * 256 + col]), a3);
  }
  for (; j < nsel; j += 4)
    a0 = fmaf(sel_w[j], b2f(vmat[(long)sel_idx[j] * 256 + col]), a0);
  partial[tid] = (a0 + a1) + (a2 + a3);
  __syncthreads();
  if (tid < 256)
    upd[r * 256 + tid] = partial[tid] + partial[256 + tid] + partial[512 + tid] + partial[768 + tid];
}

// ---------------------------------------------------------------------------
// mlp: edges_out = relu([e, upd] @ w1 + b1) @ w2 + b2   (f32, one block/row)
// ---------------------------------------------------------------------------
__global__ __launch_bounds__(256)
void mlp_kernel(const float* __restrict__ e, const float* __restrict__ upd,
                const float* __restrict__ w1, const float* __restrict__ b1,
                const float* __restrict__ w2, const float* __restrict__ b2,
                float* __restrict__ eout, u16* __restrict__ eb) {
  __shared__ float ecat[512];
  __shared__ float h[256];
  const int t = threadIdx.x;
  const long r = blockIdx.x;
  ecat[t] = e[r * 256 + t];
  ecat[256 + t] = upd[r * 256 + t];
  __syncthreads();
  float acc = b1[t];
#pragma unroll 8
  for (int kk = 0; kk < 512; ++kk) acc = fmaf(ecat[kk], w1[kk * 256 + t], acc);
  h[t] = fmaxf(acc, 0.f);
  __syncthreads();
  float a2 = b2[t];
#pragma unroll 8
  for (int kk = 0; kk < 256; ++kk) a2 = fmaf(h[kk], w2[kk * 256 + t], a2);
  eout[r * 256 + t] = a2;
  eb[r * 256 + t] = f2b(a2);
}

// ---------------------------------------------------------------------------
// g2: per row of dots2 [65536,1024]: softmax, top-ke mask, write H.
// One wave per row, 16 f32/lane, 32-step binary search on f32 monotone key.
// ---------------------------------------------------------------------------
__global__ __launch_bounds__(256)
void g2_kernel(const float* __restrict__ d2, const int* __restrict__ kep,
               float* __restrict__ H) {
  const int lane = threadIdx.x & 63, wid = threadIdx.x >> 6;
  const long row = (long)blockIdx.x * 4 + wid;
  const int ke = *kep;
  const float4* src = reinterpret_cast<const float4*>(d2 + row * 1024);
  float4 q0 = src[lane], q1 = src[64 + lane], q2v = src[128 + lane], q3 = src[192 + lane];
  float x[16] = {q0.x, q0.y, q0.z, q0.w, q1.x, q1.y, q1.z, q1.w,
                 q2v.x, q2v.y, q2v.z, q2v.w, q3.x, q3.y, q3.z, q3.w};
  float mx = x[0];
#pragma unroll
  for (int i = 1; i < 16; i++) mx = fmaxf(mx, x[i]);
  for (int sh = 1; sh < 64; sh <<= 1) mx = fmaxf(mx, __shfl_xor(mx, sh));
  float p[16];
  float se = 0.f;
#pragma unroll
  for (int i = 0; i < 16; i++) { p[i] = expf(x[i] - mx); se += p[i]; }
  for (int sh = 1; sh < 64; sh <<= 1) se += __shfl_xor(se, sh);
  const float invs = 1.f / se;
  u32 key[16];
#pragma unroll
  for (int i = 0; i < 16; i++) {
    u32 u = __builtin_bit_cast(u32, x[i]);
    key[i] = u ^ ((u >> 31) ? 0xFFFFFFFFu : 0x80000000u);
  }
  u32 lo = 0;
  for (int b = 31; b >= 0; --b) {
    u32 t = lo | (1u << b);
    int cnt = 0;
#pragma unroll
    for (int i = 0; i < 16; i++) cnt += (key[i] >= t);
    for (int sh = 1; sh < 64; sh <<= 1) cnt += __shfl_xor(cnt, sh);
    if (cnt >= ke) lo = t;
  }
  float4 o0, o1, o2, o3;
  o0.x = key[0] >= lo ? p[0] * invs : 0.f;
  o0.y = key[1] >= lo ? p[1] * invs : 0.f;
  o0.z = key[2] >= lo ? p[2] * invs : 0.f;
  o0.w = key[3] >= lo ? p[3] * invs : 0.f;
  o1.x = key[4] >= lo ? p[4] * invs : 0.f;
  o1.y = key[5] >= lo ? p[5] * invs : 0.f;
  o1.z = key[6] >= lo ? p[6] * invs : 0.f;
  o1.w = key[7] >= lo ? p[7] * invs : 0.f;
  o2.x = key[8] >= lo ? p[8] * invs : 0.f;
  o2.y = key[9] >= lo ? p[9] * invs : 0.f;
  o2.z = key[10] >= lo ? p[10] * invs : 0.f;
  o2.w = key[11] >= lo ? p[11] * invs : 0.f;
  o3.x = key[12] >= lo ? p[12] * invs : 0.f;
  o3.y = key[13] >= lo ? p[13] * invs : 0.f;
  o3.z = key[14] >= lo ? p[14] * invs : 0.f;
  o3.w = key[15] >= lo ? p[15] * invs : 0.f;
  float4* dst = reinterpret_cast<float4*>(H + row * 1024);
  dst[lane] = o0;
  dst[64 + lane] = o1;
  dst[128 + lane] = o2;
  dst[192 + lane] = o3;
}

// ---------------------------------------------------------------------------
extern "C" void kernel_launch(void* const* d_in, const int* in_sizes, int n_in,
                              void* d_out, int out_size, void* d_ws, size_t ws_size,
                              hipStream_t stream) {
  (void)in_sizes; (void)n_in; (void)out_size; (void)d_ws; (void)ws_size;

  float* out = (float*)d_out;
  float* out_edges = out;                       // [1024,256]
  float* out_H = out + NSL * DD;                // [65536,1024]
  float* out_d2 = out_H + NN * NSL;             // [65536,1024]

  // scratch carved from d_out (regions are dead until their writer runs):
  // H region: dots bf16 (134MB) + q2 bf16 (32MB) + small block; overwritten by g2 last.
  char* Hb = (char*)out_H;
  u16* dots = (u16*)Hb;                          // 1024*65536*2
  u16* q2b = (u16*)(Hb + 134217728L);            // 65536*256*2
  char* smb = Hb + 167772160L;
  u16* wcat = (u16*)smb;      smb += 768 * 256 * 2;
  float* bcat = (float*)smb;  smb += 768 * 4;
  float* e_f = (float*)smb;   smb += 1024 * 256 * 4;
  u16* e_b = (u16*)smb;       smb += 1024 * 256 * 2;
  u16* q_b = (u16*)smb;       smb += 1024 * 256 * 2;
  float* updf = (float*)smb;  smb += 1024 * 256 * 4;
  u16* edg_b = (u16*)smb;     smb += 1024 * 256 * 2;
  u16* k2_b = (u16*)smb;      smb += 1024 * 256 * 2;
  // dots2 region: x_ln, k, v bf16 (32MB each); overwritten by gemm<3>.
  char* Db = (char*)out_d2;
  u16* xln = (u16*)Db;
  u16* kb_ = (u16*)(Db + 33554432L);
  u16* vb_ = (u16*)(Db + 67108864L);

  prep_w_kernel<<<768, 256, 0, stream>>>(
      (const float*)d_in[4], (const float*)d_in[6], (const float*)d_in[8],
      (const float*)d_in[5], (const float*)d_in[7], (const float*)d_in[9], wcat, bcat);
  edges_e_kernel<<<256, 256, 0, stream>>>(
      (const float*)d_in[1], (const float*)d_in[2], (const float*)d_in[3],
      (const float*)d_in[16], (const float*)d_in[17], e_f, e_b);
  ln_x_kernel<<<16384, 256, 0, stream>>>(
      (const float*)d_in[0], (const float*)d_in[14], (const float*)d_in[15], xln);
  gemm_bt<1><<<dim3(2, 8), 256, 0, stream>>>(e_b, wcat + 512 * 256, bcat + 512, 1.f,
                                             q_b, nullptr, nullptr, nullptr);
  gemm_bt<0><<<dim3(6, 512), 256, 0, stream>>>(xln, wcat, bcat, 1.f,
                                               kb_, vb_, q2b, nullptr);
  gemm_bt<2><<<dim3(512, 8), 256, 0, stream>>>(q_b, kb_, nullptr, 0.0625f,
                                               dots, nullptr, nullptr, nullptr);
  d2d3_kernel<<<1024, 1024, 0, stream>>>(dots, vb_, (const int*)d_in[18], updf);
  mlp_kernel<<<1024, 256, 0, stream>>>(e_f, updf,
                                       (const float*)d_in[10], (const float*)d_in[11],
                                       (const float*)d_in[12], (const float*)d_in[13],
                                       out_edges, edg_b);
  gemm_bt<1><<<dim3(2, 8), 256, 0, stream>>>(edg_b, wcat, bcat, 1.f,
                                             k2_b, nullptr, nullptr, nullptr);
  gemm_bt<3><<<dim3(8, 512), 256, 0, stream>>>(q2b, k2_b, nullptr, 0.0625f,
                                               nullptr, nullptr, nullptr, out_d2);
  g2_kernel<<<16384, 256, 0, stream>>>(out_d2, (const int*)d_in[19], out_H);
}

// Round 5
// 741.583 us; speedup vs baseline: 1.1101x; 1.0490x over previous
//
#include <hip/hip_runtime.h>
#include <hip/hip_bf16.h>
#include <stdint.h>

// ---------------------------------------------------------------------------
// HConstructor: slot-attention-like block on MI355X.
//   inputs [65536,256], noise [1024,256] -> edges [1024,256], H [65536,1024],
//   dots2 [65536,1024].
// Pipeline (all on `stream`, scratch carved from dead regions of d_out):
//   prep_w   : Wcat^T = [wk|wv|wq]^T as bf16 [768,256], bias cat
//   edges_e  : edges = mu + exp(ls)*noise ; e = LN(edges)  (f32 + bf16)
//   ln_x     : x = LN(inputs) -> bf16 [65536,256]
//   gemm<1>  : q  = relu(e @ wq + bq)           [1024,256]  bf16
//   gemm<0>  : k,v = relu(x@wk/v + b), q2 = x@wq+bq 768-wide routed epilogue
//   gemm<2>  : dots = (q @ k^T) * 1/16 -> bf16 [1024,65536] (scratch)
//   d2d3     : per row (1024 thr): keys staged in LDS as per-thread quads
//              (controlled spill; compiler kept rematerializing global loads
//              when we tried registers -> 16x row re-read, ~290us).  Fixed
//              softmax shift C=8 (dots>=0 since q,k relu'd).  16-step rank
//              search reads own quads via conflict-free ds_read_b128.
//   mlp      : edges_out = relu([e,upd]@w1+b1)@w2+b2 -> OUT + bf16
//   gemm<1>  : k2 = relu(edges_out @ wk + bk)   [1024,256]  bf16
//   gemm<3>  : dots2 = (q2 @ k2^T) * 1/16 -> OUT f32
//   g2       : H = softmax(dots2) * top32-mask -> OUT
// ---------------------------------------------------------------------------

#define DEV __device__ __forceinline__

typedef uint32_t u32;
typedef uint16_t u16;
typedef __bf16 v8bf __attribute__((ext_vector_type(8)));
typedef float v4f __attribute__((ext_vector_type(4)));

static constexpr long NN = 65536;
static constexpr long DD = 256;
static constexpr long NSL = 1024;

DEV u16 f2b(float f) {
  u32 u = __builtin_bit_cast(u32, f);
  u32 r = (u + 0x7FFFu + ((u >> 16) & 1u)) >> 16;
  return (u16)r;
}
DEV float b2f(u16 h) { u32 u = ((u32)h) << 16; return __builtin_bit_cast(float, u); }
// bf16 bits (as u32 low16) -> monotone sortable 16-bit key
DEV u32 b2k(u32 b) { return b ^ (0x8000u + 0x7FFFu * (b >> 15)); }
DEV float k2fv(u32 k) {
  u16 b = (k & 0x8000u) ? (u16)(k ^ 0x8000u) : (u16)(k ^ 0xFFFFu);
  return b2f(b);
}

// ---------------------------------------------------------------------------
// Generic  C[M,N] = epilogue(A[M,256] @ B[N,256]^T)   (bf16 in, MFMA 16x16x32)
// 128x128 tile, BK=64, 4 waves (2x2), XOR-swizzled LDS (16B chunk ^ row&7).
// EPI 0: +biascat, relu for cols<512, route cols {0:k,1:v,2:q2} bf16 [M,256]
// EPI 1: +bias, relu, bf16 out [M,256]
// EPI 2: *scale, bf16 out ld=65536
// EPI 3: *scale, f32 out ld=1024
// ---------------------------------------------------------------------------
template <int EPI>
__global__ __launch_bounds__(256, 2)
void gemm_bt(const u16* __restrict__ A, const u16* __restrict__ B,
             const float* __restrict__ bias, float scale,
             u16* __restrict__ ob0, u16* __restrict__ ob1, u16* __restrict__ ob2,
             float* __restrict__ of) {
  __shared__ __align__(16) u16 As[128 * 64];
  __shared__ __align__(16) u16 Bs[128 * 64];
  const int tid = threadIdx.x;
  const int lane = tid & 63;
  const int l15 = lane & 15;
  const int l4 = lane >> 4;
  const int wid = tid >> 6;
  const int wm = wid >> 1, wn = wid & 1;
  const long m0 = (long)blockIdx.y * 128;
  const long n0 = (long)blockIdx.x * 128;

  v4f acc[4][4] = {};

  for (int kb = 0; kb < 256; kb += 64) {
    __syncthreads();
#pragma unroll
    for (int i = 0; i < 4; i++) {
      int cid = tid + 256 * i;          // 1024 16B-chunks per tile
      int row = cid >> 3, ch = cid & 7; // 8 chunks per 64-col row
      int sch = ch ^ (row & 7);
      uint4 da = *reinterpret_cast<const uint4*>(A + (m0 + row) * 256 + kb + ch * 8);
      *reinterpret_cast<uint4*>(&As[row * 64 + sch * 8]) = da;
      uint4 db = *reinterpret_cast<const uint4*>(B + (n0 + row) * 256 + kb + ch * 8);
      *reinterpret_cast<uint4*>(&Bs[row * 64 + sch * 8]) = db;
    }
    __syncthreads();
#pragma unroll
    for (int ks = 0; ks < 2; ks++) {
      v8bf af[4], bfr[4];
#pragma unroll
      for (int m = 0; m < 4; m++) {
        int row = wm * 64 + m * 16 + l15;
        int sch = (ks * 4 + l4) ^ (row & 7);
        af[m] = *reinterpret_cast<const v8bf*>(&As[row * 64 + sch * 8]);
      }
#pragma unroll
      for (int n = 0; n < 4; n++) {
        int row = wn * 64 + n * 16 + l15;
        int sch = (ks * 4 + l4) ^ (row & 7);
        bfr[n] = *reinterpret_cast<const v8bf*>(&Bs[row * 64 + sch * 8]);
      }
#pragma unroll
      for (int m = 0; m < 4; m++)
#pragma unroll
        for (int n = 0; n < 4; n++)
          acc[m][n] = __builtin_amdgcn_mfma_f32_16x16x32_bf16(af[m], bfr[n], acc[m][n], 0, 0, 0);
    }
  }

  const int r4 = l4 * 4;
#pragma unroll
  for (int m = 0; m < 4; m++) {
#pragma unroll
    for (int n = 0; n < 4; n++) {
#pragma unroll
      for (int r = 0; r < 4; r++) {
        long grow = m0 + wm * 64 + m * 16 + r4 + r;
        long gcol = n0 + wn * 64 + n * 16 + l15;
        float v = acc[m][n][r];
        if constexpr (EPI == 0) {
          v += bias[gcol];
          int which = (int)(gcol >> 8);
          long jj = gcol & 255;
          if (which < 2) v = fmaxf(v, 0.f);
          u16 hv = f2b(v);
          if (which == 0) ob0[grow * 256 + jj] = hv;
          else if (which == 1) ob1[grow * 256 + jj] = hv;
          else ob2[grow * 256 + jj] = hv;
        } else if constexpr (EPI == 1) {
          v += bias[gcol];
          v = fmaxf(v, 0.f);
          ob0[grow * 256 + gcol] = f2b(v);
        } else if constexpr (EPI == 2) {
          ob0[grow * 65536 + gcol] = f2b(v * scale);
        } else {
          of[grow * 1024 + gcol] = v * scale;
        }
      }
    }
  }
}

// ---------------------------------------------------------------------------
// Weight prep: Wcat^T bf16 [768,256] rows = [wk cols | wv cols | wq cols]
// ---------------------------------------------------------------------------
__global__ __launch_bounds__(256)
void prep_w_kernel(const float* __restrict__ wq, const float* __restrict__ wk,
                   const float* __restrict__ wv, const float* __restrict__ bq,
                   const float* __restrict__ bk, const float* __restrict__ bv,
                   u16* __restrict__ wcat, float* __restrict__ bcat) {
  int n = blockIdx.x;
  int t = threadIdx.x;
  const float* W = (n < 256) ? wk : (n < 512) ? wv : wq;
  int jj = n & 255;
  wcat[n * 256 + t] = f2b(W[t * 256 + jj]);
  if (t == 0) {
    const float* Bb = (n < 256) ? bk : (n < 512) ? bv : bq;
    bcat[n] = Bb[jj];
  }
}

// ---------------------------------------------------------------------------
// x = LayerNorm(inputs) -> bf16.  One wave per row (4 f32 per lane).
// ---------------------------------------------------------------------------
__global__ __launch_bounds__(256)
void ln_x_kernel(const float* __restrict__ x, const float* __restrict__ lw,
                 const float* __restrict__ lb, u16* __restrict__ out) {
  const int lane = threadIdx.x & 63, wid = threadIdx.x >> 6;
  const long row = (long)blockIdx.x * 4 + wid;
  float4 v = reinterpret_cast<const float4*>(x + row * 256)[lane];
  float s = v.x + v.y + v.z + v.w;
  for (int sh = 1; sh < 64; sh <<= 1) s += __shfl_xor(s, sh);
  float mu = s * (1.f / 256.f);
  float dx = v.x - mu, dy = v.y - mu, dz = v.z - mu, dw = v.w - mu;
  float q = dx * dx + dy * dy + dz * dz + dw * dw;
  for (int sh = 1; sh < 64; sh <<= 1) q += __shfl_xor(q, sh);
  float rs = rsqrtf(q * (1.f / 256.f) + 1e-5f);
  float4 wv = reinterpret_cast<const float4*>(lw)[lane];
  float4 bv = reinterpret_cast<const float4*>(lb)[lane];
  ushort4 o4;
  o4.x = f2b(dx * rs * wv.x + bv.x);
  o4.y = f2b(dy * rs * wv.y + bv.y);
  o4.z = f2b(dz * rs * wv.z + bv.z);
  o4.w = f2b(dw * rs * wv.w + bv.w);
  reinterpret_cast<ushort4*>(out + row * 256)[lane] = o4;
}

// ---------------------------------------------------------------------------
// edges = mu + exp(ls)*noise ; e = LayerNorm(edges) -> f32 + bf16
// ---------------------------------------------------------------------------
__global__ __launch_bounds__(256)
void edges_e_kernel(const float* __restrict__ noise, const float* __restrict__ emu,
                    const float* __restrict__ els, const float* __restrict__ lw,
                    const float* __restrict__ lb, float* __restrict__ e_f,
                    u16* __restrict__ e_b) {
  const int lane = threadIdx.x & 63, wid = threadIdx.x >> 6;
  const long row = (long)blockIdx.x * 4 + wid;
  float4 nz = reinterpret_cast<const float4*>(noise + row * 256)[lane];
  float4 mu4 = reinterpret_cast<const float4*>(emu)[lane];
  float4 ls4 = reinterpret_cast<const float4*>(els)[lane];
  float4 ed;
  ed.x = mu4.x + expf(ls4.x) * nz.x;
  ed.y = mu4.y + expf(ls4.y) * nz.y;
  ed.z = mu4.z + expf(ls4.z) * nz.z;
  ed.w = mu4.w + expf(ls4.w) * nz.w;
  float s = ed.x + ed.y + ed.z + ed.w;
  for (int sh = 1; sh < 64; sh <<= 1) s += __shfl_xor(s, sh);
  float mu = s * (1.f / 256.f);
  float dx = ed.x - mu, dy = ed.y - mu, dz = ed.z - mu, dw = ed.w - mu;
  float qv = dx * dx + dy * dy + dz * dz + dw * dw;
  for (int sh = 1; sh < 64; sh <<= 1) qv += __shfl_xor(qv, sh);
  float rs = rsqrtf(qv * (1.f / 256.f) + 1e-5f);
  float4 wv = reinterpret_cast<const float4*>(lw)[lane];
  float4 bv = reinterpret_cast<const float4*>(lb)[lane];
  float4 ef;
  ef.x = dx * rs * wv.x + bv.x;
  ef.y = dy * rs * wv.y + bv.y;
  ef.z = dz * rs * wv.z + bv.z;
  ef.w = dw * rs * wv.w + bv.w;
  reinterpret_cast<float4*>(e_f + row * 256)[lane] = ef;
  ushort4 o4;
  o4.x = f2b(ef.x); o4.y = f2b(ef.y); o4.z = f2b(ef.z); o4.w = f2b(ef.w);
  reinterpret_cast<ushort4*>(e_b + row * 256)[lane] = o4;
}

// ---------------------------------------------------------------------------
// d2d3: one block (1024 threads = 16 waves) per q-row.
// The 65536 monotone 16-bit keys live in LDS as per-thread quads: quad q of
// thread t at SK4[q*1024 + t] (wave reads 64x16B contiguous -> conflict-free,
// and each thread only reads ITS OWN quads -> no coherence barriers).
// Softmax uses FIXED shift C=8 (dots >= 0 because q,k are relu'd; values
// ~O(5), exp(x-8) never overflows/underflows) -> no max pass needed.
// 16-step rank-kn binary search + tie counts + selection read quads from
// LDS; gather partials alias the dead key region.
// ---------------------------------------------------------------------------
struct D3Shm {
  uint4 SK4[8192];        // 128 KiB keys
  u32 sel_idx[1152];
  float sel_w[1152];
  u32 ured[2][16];
  u32 uredG[16];
  u32 uredE[16];
  float fred[16];
  u32 scnt;
};

__global__ __launch_bounds__(1024, 4)
void d2d3_kernel(const u16* __restrict__ dots, const u16* __restrict__ vmat,
                 const int* __restrict__ knp, float* __restrict__ upd) {
  extern __shared__ char d3smem[];
  D3Shm* S = reinterpret_cast<D3Shm*>(d3smem);
  const int tid = threadIdx.x, lane = tid & 63, wid = tid >> 6;
  const long r = blockIdx.x;
  const int kn = *knp;
  if (tid == 0) S->scnt = 0;

  const float C = 8.f;  // fixed softmax shift (dots >= 0, O(5) magnitude)
  const uint4* src = reinterpret_cast<const uint4*>(dots + r * 65536);

  // ---- load row once: convert to keys, stage quads in LDS, sum-exp ----
  float se = 0.f;
#pragma unroll
  for (int q = 0; q < 8; q++) {
    uint4 d = src[tid + 1024 * q];
    u32 w0 = b2k(d.x & 0xffffu) | (b2k(d.x >> 16) << 16);
    u32 w1 = b2k(d.y & 0xffffu) | (b2k(d.y >> 16) << 16);
    u32 w2 = b2k(d.z & 0xffffu) | (b2k(d.z >> 16) << 16);
    u32 w3 = b2k(d.w & 0xffffu) | (b2k(d.w >> 16) << 16);
    uint4 kq; kq.x = w0; kq.y = w1; kq.z = w2; kq.w = w3;
    S->SK4[q * 1024 + tid] = kq;
    se += expf(k2fv(w0 & 0xffffu) - C) + expf(k2fv(w0 >> 16) - C)
        + expf(k2fv(w1 & 0xffffu) - C) + expf(k2fv(w1 >> 16) - C)
        + expf(k2fv(w2 & 0xffffu) - C) + expf(k2fv(w2 >> 16) - C)
        + expf(k2fv(w3 & 0xffffu) - C) + expf(k2fv(w3 >> 16) - C);
  }
  for (int sh = 1; sh < 64; sh <<= 1) se += __shfl_xor(se, sh);
  if (lane == 0) S->fred[wid] = se;

  // ---- 16-step binary search for rank-kn threshold (1 barrier/step) ----
  u32 lo = 0;
  for (int b = 15; b >= 0; --b) {
    const u32 t = lo | (1u << b);
    const u32 th = t << 16;
    u32 c = 0;
#pragma unroll
    for (int q = 0; q < 8; q++) {
      uint4 kq = S->SK4[q * 1024 + tid];
      c += (u32)((kq.x & 0xffffu) >= t) + (u32)(kq.x >= th);
      c += (u32)((kq.y & 0xffffu) >= t) + (u32)(kq.y >= th);
      c += (u32)((kq.z & 0xffffu) >= t) + (u32)(kq.z >= th);
      c += (u32)((kq.w & 0xffffu) >= t) + (u32)(kq.w >= th);
    }
    for (int sh = 1; sh < 64; sh <<= 1) c += (u32)__shfl_xor((int)c, sh);
    if (lane == 0) S->ured[b & 1][wid] = c;
    __syncthreads();
    u32 tot = 0;
#pragma unroll
    for (int i = 0; i < 16; i++) tot += S->ured[b & 1][i];
    if (tot >= (u32)kn) lo = t;
  }
  const u32 thr = lo;

  // ---- counts >thr and ==thr for fractional tie weighting ----
  const u32 thrhF = (thr << 16) | 0xffffu;
  u32 cg = 0, ce = 0;
#pragma unroll
  for (int q = 0; q < 8; q++) {
    uint4 kq = S->SK4[q * 1024 + tid];
    u32 kl, kh;
    kl = kq.x & 0xffffu; kh = kq.x >> 16;
    cg += (u32)(kl > thr) + (u32)(kq.x > thrhF); ce += (u32)(kl == thr) + (u32)(kh == thr);
    kl = kq.y & 0xffffu; kh = kq.y >> 16;
    cg += (u32)(kl > thr) + (u32)(kq.y > thrhF); ce += (u32)(kl == thr) + (u32)(kh == thr);
    kl = kq.z & 0xffffu; kh = kq.z >> 16;
    cg += (u32)(kl > thr) + (u32)(kq.z > thrhF); ce += (u32)(kl == thr) + (u32)(kh == thr);
    kl = kq.w & 0xffffu; kh = kq.w >> 16;
    cg += (u32)(kl > thr) + (u32)(kq.w > thrhF); ce += (u32)(kl == thr) + (u32)(kh == thr);
  }
  for (int sh = 1; sh < 64; sh <<= 1) {
    cg += (u32)__shfl_xor((int)cg, sh);
    ce += (u32)__shfl_xor((int)ce, sh);
  }
  if (lane == 0) { S->uredG[wid] = cg; S->uredE[wid] = ce; }
  __syncthreads();
  u32 CG = 0, CE = 0;
  float SE = 0.f;
#pragma unroll
  for (int i = 0; i < 16; i++) { CG += S->uredG[i]; CE += S->uredE[i]; SE += S->fred[i]; }
  const float frac = (float)(int)((u32)kn - CG) / (float)CE;
  const float invs = 1.f / SE;
  const float wnorm = 1.f / (1.f + 65536.f * 1e-8f);

  // ---- selection: keys >= thr -> (global idx, weight) list ----
#pragma unroll
  for (int q = 0; q < 8; q++) {
    uint4 kq = S->SK4[q * 1024 + tid];
    const u32 base = (u32)(tid + 1024 * q) * 8;
    u32 kk[8] = {kq.x & 0xffffu, kq.x >> 16, kq.y & 0xffffu, kq.y >> 16,
                 kq.z & 0xffffu, kq.z >> 16, kq.w & 0xffffu, kq.w >> 16};
#pragma unroll
    for (int j = 0; j < 8; j++) {
      if (kk[j] >= thr) {
        float w = (expf(k2fv(kk[j]) - C) * invs + 1e-8f) * wnorm;
        if (kk[j] == thr) w *= frac;
        u32 p = atomicAdd(&S->scnt, 1u);
        if (p < 1152u) { S->sel_idx[p] = base + (u32)j; S->sel_w[p] = w; }
      }
    }
  }
  __syncthreads();
  const u32 nsel = S->scnt < 1152u ? S->scnt : 1152u;

  // ---- sparse accumulate: 4 groups x 256 cols, 4-deep ILP, combine ----
  // partial[] aliases the (now dead) key region.
  float* partial = reinterpret_cast<float*>(S->SK4);
  const int g = tid >> 8, col = tid & 255;
  float a0 = 0.f, a1 = 0.f, a2 = 0.f, a3 = 0.f;
  u32 j = (u32)g;
  for (; j + 12 < nsel; j += 16) {
    a0 = fmaf(S->sel_w[j], b2f(vmat[(long)S->sel_idx[j] * 256 + col]), a0);
    a1 = fmaf(S->sel_w[j + 4], b2f(vmat[(long)S->sel_idx[j + 4] * 256 + col]), a1);
    a2 = fmaf(S->sel_w[j + 8], b2f(vmat[(long)S->sel_idx[j + 8] * 256 + col]), a2);
    a3 = fmaf(S->sel_w[j + 12], b2f(vmat[(long)S->sel_idx[j + 12] * 256 + col]), a3);
  }
  for (; j < nsel; j += 4)
    a0 = fmaf(S->sel_w[j], b2f(vmat[(long)S->sel_idx[j] * 256 + col]), a0);
  partial[tid] = (a0 + a1) + (a2 + a3);
  __syncthreads();
  if (tid < 256)
    upd[r * 256 + tid] = partial[tid] + partial[256 + tid] + partial[512 + tid] + partial[768 + tid];
}

// ---------------------------------------------------------------------------
// mlp: edges_out = relu([e, upd] @ w1 + b1) @ w2 + b2   (f32, one block/row)
// ---------------------------------------------------------------------------
__global__ __launch_bounds__(256)
void mlp_kernel(const float* __restrict__ e, const float* __restrict__ upd,
                const float* __restrict__ w1, const float* __restrict__ b1,
                const float* __restrict__ w2, const float* __restrict__ b2,
                float* __restrict__ eout, u16* __restrict__ eb) {
  __shared__ float ecat[512];
  __shared__ float h[256];
  const int t = threadIdx.x;
  const long r = blockIdx.x;
  ecat[t] = e[r * 256 + t];
  ecat[256 + t] = upd[r * 256 + t];
  __syncthreads();
  float acc = b1[t];
#pragma unroll 8
  for (int kk = 0; kk < 512; ++kk) acc = fmaf(ecat[kk], w1[kk * 256 + t], acc);
  h[t] = fmaxf(acc, 0.f);
  __syncthreads();
  float a2 = b2[t];
#pragma unroll 8
  for (int kk = 0; kk < 256; ++kk) a2 = fmaf(h[kk], w2[kk * 256 + t], a2);
  eout[r * 256 + t] = a2;
  eb[r * 256 + t] = f2b(a2);
}

// ---------------------------------------------------------------------------
// g2: per row of dots2 [65536,1024]: softmax, top-ke mask, write H.
// One wave per row, 16 f32/lane, 32-step binary search on f32 monotone key.
// ---------------------------------------------------------------------------
__global__ __launch_bounds__(256)
void g2_kernel(const float* __restrict__ d2, const int* __restrict__ kep,
               float* __restrict__ H) {
  const int lane = threadIdx.x & 63, wid = threadIdx.x >> 6;
  const long row = (long)blockIdx.x * 4 + wid;
  const int ke = *kep;
  const float4* src = reinterpret_cast<const float4*>(d2 + row * 1024);
  float4 q0 = src[lane], q1 = src[64 + lane], q2v = src[128 + lane], q3 = src[192 + lane];
  float x[16] = {q0.x, q0.y, q0.z, q0.w, q1.x, q1.y, q1.z, q1.w,
                 q2v.x, q2v.y, q2v.z, q2v.w, q3.x, q3.y, q3.z, q3.w};
  float mx = x[0];
#pragma unroll
  for (int i = 1; i < 16; i++) mx = fmaxf(mx, x[i]);
  for (int sh = 1; sh < 64; sh <<= 1) mx = fmaxf(mx, __shfl_xor(mx, sh));
  float p[16];
  float se = 0.f;
#pragma unroll
  for (int i = 0; i < 16; i++) { p[i] = expf(x[i] - mx); se += p[i]; }
  for (int sh = 1; sh < 64; sh <<= 1) se += __shfl_xor(se, sh);
  const float invs = 1.f / se;
  u32 key[16];
#pragma unroll
  for (int i = 0; i < 16; i++) {
    u32 u = __builtin_bit_cast(u32, x[i]);
    key[i] = u ^ ((u >> 31) ? 0xFFFFFFFFu : 0x80000000u);
  }
  u32 lo = 0;
  for (int b = 31; b >= 0; --b) {
    u32 t = lo | (1u << b);
    int cnt = 0;
#pragma unroll
    for (int i = 0; i < 16; i++) cnt += (key[i] >= t);
    for (int sh = 1; sh < 64; sh <<= 1) cnt += __shfl_xor(cnt, sh);
    if (cnt >= ke) lo = t;
  }
  float4 o0, o1, o2, o3;
  o0.x = key[0] >= lo ? p[0] * invs : 0.f;
  o0.y = key[1] >= lo ? p[1] * invs : 0.f;
  o0.z = key[2] >= lo ? p[2] * invs : 0.f;
  o0.w = key[3] >= lo ? p[3] * invs : 0.f;
  o1.x = key[4] >= lo ? p[4] * invs : 0.f;
  o1.y = key[5] >= lo ? p[5] * invs : 0.f;
  o1.z = key[6] >= lo ? p[6] * invs : 0.f;
  o1.w = key[7] >= lo ? p[7] * invs : 0.f;
  o2.x = key[8] >= lo ? p[8] * invs : 0.f;
  o2.y = key[9] >= lo ? p[9] * invs : 0.f;
  o2.z = key[10] >= lo ? p[10] * invs : 0.f;
  o2.w = key[11] >= lo ? p[11] * invs : 0.f;
  o3.x = key[12] >= lo ? p[12] * invs : 0.f;
  o3.y = key[13] >= lo ? p[13] * invs : 0.f;
  o3.z = key[14] >= lo ? p[14] * invs : 0.f;
  o3.w = key[15] >= lo ? p[15] * invs : 0.f;
  float4* dst = reinterpret_cast<float4*>(H + row * 1024);
  dst[lane] = o0;
  dst[64 + lane] = o1;
  dst[128 + lane] = o2;
  dst[192 + lane] = o3;
}

// ---------------------------------------------------------------------------
extern "C" void kernel_launch(void* const* d_in, const int* in_sizes, int n_in,
                              void* d_out, int out_size, void* d_ws, size_t ws_size,
                              hipStream_t stream) {
  (void)in_sizes; (void)n_in; (void)out_size; (void)d_ws; (void)ws_size;

  float* out = (float*)d_out;
  float* out_edges = out;                       // [1024,256]
  float* out_H = out + NSL * DD;                // [65536,1024]
  float* out_d2 = out_H + NN * NSL;             // [65536,1024]

  // scratch carved from d_out (regions are dead until their writer runs):
  // H region: dots bf16 (134MB) + q2 bf16 (32MB) + small block; overwritten by g2 last.
  char* Hb = (char*)out_H;
  u16* dots = (u16*)Hb;                          // 1024*65536*2
  u16* q2b = (u16*)(Hb + 134217728L);            // 65536*256*2
  char* smb = Hb + 167772160L;
  u16* wcat = (u16*)smb;      smb += 768 * 256 * 2;
  float* bcat = (float*)smb;  smb += 768 * 4;
  float* e_f = (float*)smb;   smb += 1024 * 256 * 4;
  u16* e_b = (u16*)smb;       smb += 1024 * 256 * 2;
  u16* q_b = (u16*)smb;       smb += 1024 * 256 * 2;
  float* updf = (float*)smb;  smb += 1024 * 256 * 4;
  u16* edg_b = (u16*)smb;     smb += 1024 * 256 * 2;
  u16* k2_b = (u16*)smb;      smb += 1024 * 256 * 2;
  // dots2 region: x_ln, k, v bf16 (32MB each); overwritten by gemm<3>.
  char* Db = (char*)out_d2;
  u16* xln = (u16*)Db;
  u16* kb_ = (u16*)(Db + 33554432L);
  u16* vb_ = (u16*)(Db + 67108864L);

  hipFuncSetAttribute(reinterpret_cast<const void*>(d2d3_kernel),
                      hipFuncAttributeMaxDynamicSharedMemorySize,
                      (int)sizeof(D3Shm));

  prep_w_kernel<<<768, 256, 0, stream>>>(
      (const float*)d_in[4], (const float*)d_in[6], (const float*)d_in[8],
      (const float*)d_in[5], (const float*)d_in[7], (const float*)d_in[9], wcat, bcat);
  edges_e_kernel<<<256, 256, 0, stream>>>(
      (const float*)d_in[1], (const float*)d_in[2], (const float*)d_in[3],
      (const float*)d_in[16], (const float*)d_in[17], e_f, e_b);
  ln_x_kernel<<<16384, 256, 0, stream>>>(
      (const float*)d_in[0], (const float*)d_in[14], (const float*)d_in[15], xln);
  gemm_bt<1><<<dim3(2, 8), 256, 0, stream>>>(e_b, wcat + 512 * 256, bcat + 512, 1.f,
                                             q_b, nullptr, nullptr, nullptr);
  gemm_bt<0><<<dim3(6, 512), 256, 0, stream>>>(xln, wcat, bcat, 1.f,
                                               kb_, vb_, q2b, nullptr);
  gemm_bt<2><<<dim3(512, 8), 256, 0, stream>>>(q_b, kb_, nullptr, 0.0625f,
                                               dots, nullptr, nullptr, nullptr);
  d2d3_kernel<<<1024, 1024, sizeof(D3Shm), stream>>>(dots, vb_, (const int*)d_in[18], updf);
  mlp_kernel<<<1024, 256, 0, stream>>>(e_f, updf,
                                       (const float*)d_in[10], (const float*)d_in[11],
                                       (const float*)d_in[12], (const float*)d_in[13],
                                       out_edges, edg_b);
  gemm_bt<1><<<dim3(2, 8), 256, 0, stream>>>(edg_b, wcat, bcat, 1.f,
                                             k2_b, nullptr, nullptr, nullptr);
  gemm_bt<3><<<dim3(8, 512), 256, 0, stream>>>(q2b, k2_b, nullptr, 0.0625f,
                                               nullptr, nullptr, nullptr, out_d2);
  g2_kernel<<<16384, 256, 0, stream>>>(out_d2, (const int*)d_in[19], out_H);
}

// Round 6
// 647.059 us; speedup vs baseline: 1.2723x; 1.1461x over previous
//
#include <hip/hip_runtime.h>
#include <hip/hip_bf16.h>
#include <stdint.h>

// ---------------------------------------------------------------------------
// HConstructor: slot-attention-like block on MI355X.
//   inputs [65536,256], noise [1024,256] -> edges [1024,256], H [65536,1024],
//   dots2 [65536,1024].
// Pipeline (all on `stream`, scratch carved from dead regions of d_out):
//   prep_w   : Wcat^T = [wk|wv|wq]^T as bf16 [768,256], bias cat
//   edges_e  : edges = mu + exp(ls)*noise ; e = LN(edges)  (f32 + bf16)
//   ln_x     : x = LN(inputs) -> bf16 [65536,256]
//   gemm<1>  : q  = relu(e @ wq + bq)           [1024,256]  bf16
//   gemm<0>  : k,v = relu(x@wk/v + b), q2 = x@wq+bq 768-wide routed epilogue
//   gemm<2>  : dots = (q @ k^T) * 1/16 -> bf16 [1024,65536] (scratch)
//   d2d3     : per row: 2-level histogram rank-select. High-byte histogram
//              built during the load pass with LANE-INDEXED LDS copies
//              (hist[bin*16 + (lane>>2)] -> fixed bank per lane, no random
//              conflicts, unlike R3's per-wave layout); low-byte histogram
//              is one predicated pass over LDS-resident keys. Replaces the
//              16-pass binary search (R4/R5, ~255us).  Fixed softmax shift
//              C=8 (dots >= 0 since q,k relu'd).  Then sparse attn@v gather.
//   mlp      : edges_out = relu([e,upd]@w1+b1)@w2+b2 -> OUT + bf16
//   gemm<1>  : k2 = relu(edges_out @ wk + bk)   [1024,256]  bf16
//   gemm<3>  : dots2 = (q2 @ k2^T) * 1/16 -> OUT f32
//   g2       : H = softmax(dots2) * top32-mask -> OUT
// ---------------------------------------------------------------------------

#define DEV __device__ __forceinline__

typedef uint32_t u32;
typedef uint16_t u16;
typedef __bf16 v8bf __attribute__((ext_vector_type(8)));
typedef float v4f __attribute__((ext_vector_type(4)));

static constexpr long NN = 65536;
static constexpr long DD = 256;
static constexpr long NSL = 1024;

DEV u16 f2b(float f) {
  u32 u = __builtin_bit_cast(u32, f);
  u32 r = (u + 0x7FFFu + ((u >> 16) & 1u)) >> 16;
  return (u16)r;
}
DEV float b2f(u16 h) { u32 u = ((u32)h) << 16; return __builtin_bit_cast(float, u); }
// bf16 bits (as u32 low16) -> monotone sortable 16-bit key
DEV u32 b2k(u32 b) { return b ^ (0x8000u + 0x7FFFu * (b >> 15)); }
DEV float k2fv(u32 k) {
  u16 b = (k & 0x8000u) ? (u16)(k ^ 0x8000u) : (u16)(k ^ 0xFFFFu);
  return b2f(b);
}

// ---------------------------------------------------------------------------
// Generic  C[M,N] = epilogue(A[M,256] @ B[N,256]^T)   (bf16 in, MFMA 16x16x32)
// 128x128 tile, BK=64, 4 waves (2x2), XOR-swizzled LDS (16B chunk ^ row&7).
// EPI 0: +biascat, relu for cols<512, route cols {0:k,1:v,2:q2} bf16 [M,256]
// EPI 1: +bias, relu, bf16 out [M,256]
// EPI 2: *scale, bf16 out ld=65536
// EPI 3: *scale, f32 out ld=1024
// ---------------------------------------------------------------------------
template <int EPI>
__global__ __launch_bounds__(256, 2)
void gemm_bt(const u16* __restrict__ A, const u16* __restrict__ B,
             const float* __restrict__ bias, float scale,
             u16* __restrict__ ob0, u16* __restrict__ ob1, u16* __restrict__ ob2,
             float* __restrict__ of) {
  __shared__ __align__(16) u16 As[128 * 64];
  __shared__ __align__(16) u16 Bs[128 * 64];
  const int tid = threadIdx.x;
  const int lane = tid & 63;
  const int l15 = lane & 15;
  const int l4 = lane >> 4;
  const int wid = tid >> 6;
  const int wm = wid >> 1, wn = wid & 1;
  const long m0 = (long)blockIdx.y * 128;
  const long n0 = (long)blockIdx.x * 128;

  v4f acc[4][4] = {};

  for (int kb = 0; kb < 256; kb += 64) {
    __syncthreads();
#pragma unroll
    for (int i = 0; i < 4; i++) {
      int cid = tid + 256 * i;          // 1024 16B-chunks per tile
      int row = cid >> 3, ch = cid & 7; // 8 chunks per 64-col row
      int sch = ch ^ (row & 7);
      uint4 da = *reinterpret_cast<const uint4*>(A + (m0 + row) * 256 + kb + ch * 8);
      *reinterpret_cast<uint4*>(&As[row * 64 + sch * 8]) = da;
      uint4 db = *reinterpret_cast<const uint4*>(B + (n0 + row) * 256 + kb + ch * 8);
      *reinterpret_cast<uint4*>(&Bs[row * 64 + sch * 8]) = db;
    }
    __syncthreads();
#pragma unroll
    for (int ks = 0; ks < 2; ks++) {
      v8bf af[4], bfr[4];
#pragma unroll
      for (int m = 0; m < 4; m++) {
        int row = wm * 64 + m * 16 + l15;
        int sch = (ks * 4 + l4) ^ (row & 7);
        af[m] = *reinterpret_cast<const v8bf*>(&As[row * 64 + sch * 8]);
      }
#pragma unroll
      for (int n = 0; n < 4; n++) {
        int row = wn * 64 + n * 16 + l15;
        int sch = (ks * 4 + l4) ^ (row & 7);
        bfr[n] = *reinterpret_cast<const v8bf*>(&Bs[row * 64 + sch * 8]);
      }
#pragma unroll
      for (int m = 0; m < 4; m++)
#pragma unroll
        for (int n = 0; n < 4; n++)
          acc[m][n] = __builtin_amdgcn_mfma_f32_16x16x32_bf16(af[m], bfr[n], acc[m][n], 0, 0, 0);
    }
  }

  const int r4 = l4 * 4;
#pragma unroll
  for (int m = 0; m < 4; m++) {
#pragma unroll
    for (int n = 0; n < 4; n++) {
#pragma unroll
      for (int r = 0; r < 4; r++) {
        long grow = m0 + wm * 64 + m * 16 + r4 + r;
        long gcol = n0 + wn * 64 + n * 16 + l15;
        float v = acc[m][n][r];
        if constexpr (EPI == 0) {
          v += bias[gcol];
          int which = (int)(gcol >> 8);
          long jj = gcol & 255;
          if (which < 2) v = fmaxf(v, 0.f);
          u16 hv = f2b(v);
          if (which == 0) ob0[grow * 256 + jj] = hv;
          else if (which == 1) ob1[grow * 256 + jj] = hv;
          else ob2[grow * 256 + jj] = hv;
        } else if constexpr (EPI == 1) {
          v += bias[gcol];
          v = fmaxf(v, 0.f);
          ob0[grow * 256 + gcol] = f2b(v);
        } else if constexpr (EPI == 2) {
          ob0[grow * 65536 + gcol] = f2b(v * scale);
        } else {
          of[grow * 1024 + gcol] = v * scale;
        }
      }
    }
  }
}

// ---------------------------------------------------------------------------
// Weight prep: Wcat^T bf16 [768,256] rows = [wk cols | wv cols | wq cols]
// ---------------------------------------------------------------------------
__global__ __launch_bounds__(256)
void prep_w_kernel(const float* __restrict__ wq, const float* __restrict__ wk,
                   const float* __restrict__ wv, const float* __restrict__ bq,
                   const float* __restrict__ bk, const float* __restrict__ bv,
                   u16* __restrict__ wcat, float* __restrict__ bcat) {
  int n = blockIdx.x;
  int t = threadIdx.x;
  const float* W = (n < 256) ? wk : (n < 512) ? wv : wq;
  int jj = n & 255;
  wcat[n * 256 + t] = f2b(W[t * 256 + jj]);
  if (t == 0) {
    const float* Bb = (n < 256) ? bk : (n < 512) ? bv : bq;
    bcat[n] = Bb[jj];
  }
}

// ---------------------------------------------------------------------------
// x = LayerNorm(inputs) -> bf16.  One wave per row (4 f32 per lane).
// ---------------------------------------------------------------------------
__global__ __launch_bounds__(256)
void ln_x_kernel(const float* __restrict__ x, const float* __restrict__ lw,
                 const float* __restrict__ lb, u16* __restrict__ out) {
  const int lane = threadIdx.x & 63, wid = threadIdx.x >> 6;
  const long row = (long)blockIdx.x * 4 + wid;
  float4 v = reinterpret_cast<const float4*>(x + row * 256)[lane];
  float s = v.x + v.y + v.z + v.w;
  for (int sh = 1; sh < 64; sh <<= 1) s += __shfl_xor(s, sh);
  float mu = s * (1.f / 256.f);
  float dx = v.x - mu, dy = v.y - mu, dz = v.z - mu, dw = v.w - mu;
  float q = dx * dx + dy * dy + dz * dz + dw * dw;
  for (int sh = 1; sh < 64; sh <<= 1) q += __shfl_xor(q, sh);
  float rs = rsqrtf(q * (1.f / 256.f) + 1e-5f);
  float4 wv = reinterpret_cast<const float4*>(lw)[lane];
  float4 bv = reinterpret_cast<const float4*>(lb)[lane];
  ushort4 o4;
  o4.x = f2b(dx * rs * wv.x + bv.x);
  o4.y = f2b(dy * rs * wv.y + bv.y);
  o4.z = f2b(dz * rs * wv.z + bv.z);
  o4.w = f2b(dw * rs * wv.w + bv.w);
  reinterpret_cast<ushort4*>(out + row * 256)[lane] = o4;
}

// ---------------------------------------------------------------------------
// edges = mu + exp(ls)*noise ; e = LayerNorm(edges) -> f32 + bf16
// ---------------------------------------------------------------------------
__global__ __launch_bounds__(256)
void edges_e_kernel(const float* __restrict__ noise, const float* __restrict__ emu,
                    const float* __restrict__ els, const float* __restrict__ lw,
                    const float* __restrict__ lb, float* __restrict__ e_f,
                    u16* __restrict__ e_b) {
  const int lane = threadIdx.x & 63, wid = threadIdx.x >> 6;
  const long row = (long)blockIdx.x * 4 + wid;
  float4 nz = reinterpret_cast<const float4*>(noise + row * 256)[lane];
  float4 mu4 = reinterpret_cast<const float4*>(emu)[lane];
  float4 ls4 = reinterpret_cast<const float4*>(els)[lane];
  float4 ed;
  ed.x = mu4.x + expf(ls4.x) * nz.x;
  ed.y = mu4.y + expf(ls4.y) * nz.y;
  ed.z = mu4.z + expf(ls4.z) * nz.z;
  ed.w = mu4.w + expf(ls4.w) * nz.w;
  float s = ed.x + ed.y + ed.z + ed.w;
  for (int sh = 1; sh < 64; sh <<= 1) s += __shfl_xor(s, sh);
  float mu = s * (1.f / 256.f);
  float dx = ed.x - mu, dy = ed.y - mu, dz = ed.z - mu, dw = ed.w - mu;
  float qv = dx * dx + dy * dy + dz * dz + dw * dw;
  for (int sh = 1; sh < 64; sh <<= 1) qv += __shfl_xor(qv, sh);
  float rs = rsqrtf(qv * (1.f / 256.f) + 1e-5f);
  float4 wv = reinterpret_cast<const float4*>(lw)[lane];
  float4 bv = reinterpret_cast<const float4*>(lb)[lane];
  float4 ef;
  ef.x = dx * rs * wv.x + bv.x;
  ef.y = dy * rs * wv.y + bv.y;
  ef.z = dz * rs * wv.z + bv.z;
  ef.w = dw * rs * wv.w + bv.w;
  reinterpret_cast<float4*>(e_f + row * 256)[lane] = ef;
  ushort4 o4;
  o4.x = f2b(ef.x); o4.y = f2b(ef.y); o4.z = f2b(ef.z); o4.w = f2b(ef.w);
  reinterpret_cast<ushort4*>(e_b + row * 256)[lane] = o4;
}

// ---------------------------------------------------------------------------
// d2d3: one block (1024 threads = 16 waves) per q-row.
// 2-level histogram rank select:
//   load pass : row -> keys (LDS quads) + sum-exp + HIGH-byte histogram,
//               built with lane-indexed copies hist[bin*16 + (lane>>2)] so
//               each lane's atomics hit a fixed bank pair (2-4-way max).
//   scan 1    : reduce 16 copies -> c_hi; wave-0 suffix scan -> b*, Thi.
//   low pass  : predicated LOW-byte histogram of keys with high byte == b*
//               (reads own LDS quads; ~1/256 of keys hit the atomic).
//   scan 2    : -> exact thr, tie counts, frac.
//   selection : keys >= thr -> (idx, weight) list;  gather: sparse attn@v.
// Softmax uses fixed shift C=8 (dots >= 0 because q,k relu'd; magnitudes
// O(5): exp(x-8) in [e-8, ~e-2], no overflow/underflow).
// ---------------------------------------------------------------------------
struct D3Shm {
  uint4 SK4[8192];        // 128 KiB packed keys (2 x u16 per u32)
  u32 hist[256 * 16];     // 16 KiB: bin b, copy c at [b*16+c]
  u32 c_hi[256];
  u32 sel_idx[1152];
  float sel_w[1152];
  float fred[16];
  u32 sb_star, sThi, sThr;
  float sSE, sFrac;
  u32 scnt;
};

__global__ __launch_bounds__(1024, 4)
void d2d3_kernel(const u16* __restrict__ dots, const u16* __restrict__ vmat,
                 const int* __restrict__ knp, float* __restrict__ upd) {
  extern __shared__ char d3smem[];
  D3Shm* S = reinterpret_cast<D3Shm*>(d3smem);
  const int tid = threadIdx.x, lane = tid & 63, wid = tid >> 6;
  const int hc = (lane >> 2);          // 16 lane-indexed histogram copies
  const long r = blockIdx.x;
  const int kn = *knp;

  for (int i = tid; i < 4096; i += 1024) S->hist[i] = 0;
  if (tid == 0) S->scnt = 0;
  __syncthreads();

  const float C = 8.f;  // fixed softmax shift (dots >= 0, O(5) magnitude)
  const uint4* src = reinterpret_cast<const uint4*>(dots + r * 65536);

  // ---- load pass: keys -> LDS, sum-exp, high-byte histogram ----
  float se = 0.f;
#pragma unroll
  for (int q = 0; q < 8; q++) {
    uint4 d = src[tid + 1024 * q];
    u32 h[8] = {d.x & 0xffffu, d.x >> 16, d.y & 0xffffu, d.y >> 16,
                d.z & 0xffffu, d.z >> 16, d.w & 0xffffu, d.w >> 16};
    u32 k[8];
#pragma unroll
    for (int j = 0; j < 8; j++) {
      k[j] = b2k(h[j]);
      se += __expf(b2f((u16)h[j]) - C);
      atomicAdd(&S->hist[(k[j] >> 8) * 16 + hc], 1u);
    }
    uint4 kq;
    kq.x = k[0] | (k[1] << 16); kq.y = k[2] | (k[3] << 16);
    kq.z = k[4] | (k[5] << 16); kq.w = k[6] | (k[7] << 16);
    S->SK4[q * 1024 + tid] = kq;
  }
  for (int sh = 1; sh < 64; sh <<= 1) se += __shfl_xor(se, sh);
  if (lane == 0) S->fred[wid] = se;
  __syncthreads();

  // ---- reduce copies -> c_hi ----
  if (tid < 256) {
    u32 s = 0;
#pragma unroll
    for (int c = 0; c < 16; c++) s += S->hist[tid * 16 + c];
    S->c_hi[tid] = s;
  }
  __syncthreads();

  // ---- wave 0: high suffix scan -> b*, Thi;  others: re-zero hist ----
  if (tid < 64) {
    u32 s = S->c_hi[4 * tid] + S->c_hi[4 * tid + 1] + S->c_hi[4 * tid + 2] + S->c_hi[4 * tid + 3];
    u32 v = s;
    for (int off = 1; off < 64; off <<= 1) {
      u32 t = (u32)__shfl_down((int)v, off);
      if (tid + off < 64) v += t;        // inclusive suffix sum over lanes
    }
    u32 excl = v - s;
    if (v >= (u32)kn && excl < (u32)kn) {
      u32 acc = excl;
#pragma unroll
      for (int bb = 3; bb >= 0; --bb) {
        int b = 4 * tid + bb;
        u32 nb = acc + S->c_hi[b];
        if (nb >= (u32)kn) { S->sb_star = (u32)b; S->sThi = acc; break; }
        acc = nb;
      }
    }
  } else {
    for (int i = tid - 64; i < 4096; i += 960) S->hist[i] = 0;
  }
  __syncthreads();
  const u32 bstar = S->sb_star;

  // ---- low pass: predicated low-byte histogram from own LDS quads ----
#pragma unroll
  for (int q = 0; q < 8; q++) {
    uint4 kq = S->SK4[q * 1024 + tid];
    u32 w[4] = {kq.x, kq.y, kq.z, kq.w};
#pragma unroll
    for (int j = 0; j < 4; j++) {
      u32 kl = w[j] & 0xffffu, kh = w[j] >> 16;
      if ((kl >> 8) == bstar) atomicAdd(&S->hist[(kl & 255u) * 16 + hc], 1u);
      if ((kh >> 8) == bstar) atomicAdd(&S->hist[(kh & 255u) * 16 + hc], 1u);
    }
  }
  __syncthreads();
  if (tid < 256) {
    u32 s = 0;
#pragma unroll
    for (int c = 0; c < 16; c++) s += S->hist[tid * 16 + c];
    S->c_hi[tid] = s;
  }
  __syncthreads();

  // ---- wave 0: low suffix scan -> exact threshold, tie counts, SE ----
  if (tid < 64) {
    u32 s = S->c_hi[4 * tid] + S->c_hi[4 * tid + 1] + S->c_hi[4 * tid + 2] + S->c_hi[4 * tid + 3];
    u32 v = s;
    for (int off = 1; off < 64; off <<= 1) {
      u32 t = (u32)__shfl_down((int)v, off);
      if (tid + off < 64) v += t;
    }
    const u32 Thi = S->sThi;             // count(high byte > b*)
    u32 incl = v + Thi;
    u32 excl = v - s + Thi;
    if (incl >= (u32)kn && excl < (u32)kn) {
      u32 acc = excl;
#pragma unroll
      for (int bb = 3; bb >= 0; --bb) {
        int b = 4 * tid + bb;
        u32 nb = acc + S->c_hi[b];
        if (nb >= (u32)kn) {
          S->sThr = (bstar << 8) | (u32)b;
          // acc = count(key > thr), c_hi[b] = count(key == thr)
          S->sFrac = (float)(int)((u32)kn - acc) / (float)S->c_hi[b];
          break;
        }
        acc = nb;
      }
    }
    if (tid == 0) {
      float SE = 0.f;
#pragma unroll
      for (int i = 0; i < 16; i++) SE += S->fred[i];
      S->sSE = SE;
    }
  }
  __syncthreads();
  const u32 thr = S->sThr;
  const float frac = S->sFrac;
  const float invs = 1.f / S->sSE;
  const float wnorm = 1.f / (1.f + 65536.f * 1e-8f);

  // ---- selection: keys >= thr -> (global idx, weight) list ----
#pragma unroll
  for (int q = 0; q < 8; q++) {
    uint4 kq = S->SK4[q * 1024 + tid];
    const u32 base = (u32)(tid + 1024 * q) * 8;
    u32 kk[8] = {kq.x & 0xffffu, kq.x >> 16, kq.y & 0xffffu, kq.y >> 16,
                 kq.z & 0xffffu, kq.z >> 16, kq.w & 0xffffu, kq.w >> 16};
#pragma unroll
    for (int j = 0; j < 8; j++) {
      if (kk[j] >= thr) {
        float w = (__expf(k2fv(kk[j]) - C) * invs + 1e-8f) * wnorm;
        if (kk[j] == thr) w *= frac;
        u32 p = atomicAdd(&S->scnt, 1u);
        if (p < 1152u) { S->sel_idx[p] = base + (u32)j; S->sel_w[p] = w; }
      }
    }
  }
  __syncthreads();
  const u32 nsel = S->scnt < 1152u ? S->scnt : 1152u;

  // ---- sparse accumulate: 4 groups x 256 cols, 4-deep ILP, combine ----
  // partial[] aliases the (now dead) key region.
  float* partial = reinterpret_cast<float*>(S->SK4);
  const int g = tid >> 8, col = tid & 255;
  float a0 = 0.f, a1 = 0.f, a2 = 0.f, a3 = 0.f;
  u32 j = (u32)g;
  for (; j + 12 < nsel; j += 16) {
    a0 = fmaf(S->sel_w[j], b2f(vmat[(long)S->sel_idx[j] * 256 + col]), a0);
    a1 = fmaf(S->sel_w[j + 4], b2f(vmat[(long)S->sel_idx[j + 4] * 256 + col]), a1);
    a2 = fmaf(S->sel_w[j + 8], b2f(vmat[(long)S->sel_idx[j + 8] * 256 + col]), a2);
    a3 = fmaf(S->sel_w[j + 12], b2f(vmat[(long)S->sel_idx[j + 12] * 256 + col]), a3);
  }
  for (; j < nsel; j += 4)
    a0 = fmaf(S->sel_w[j], b2f(vmat[(long)S->sel_idx[j] * 256 + col]), a0);
  partial[tid] = (a0 + a1) + (a2 + a3);
  __syncthreads();
  if (tid < 256)
    upd[r * 256 + tid] = partial[tid] + partial[256 + tid] + partial[512 + tid] + partial[768 + tid];
}

// ---------------------------------------------------------------------------
// mlp: edges_out = relu([e, upd] @ w1 + b1) @ w2 + b2   (f32, one block/row)
// ---------------------------------------------------------------------------
__global__ __launch_bounds__(256)
void mlp_kernel(const float* __restrict__ e, const float* __restrict__ upd,
                const float* __restrict__ w1, const float* __restrict__ b1,
                const float* __restrict__ w2, const float* __restrict__ b2,
                float* __restrict__ eout, u16* __restrict__ eb) {
  __shared__ float ecat[512];
  __shared__ float h[256];
  const int t = threadIdx.x;
  const long r = blockIdx.x;
  ecat[t] = e[r * 256 + t];
  ecat[256 + t] = upd[r * 256 + t];
  __syncthreads();
  float acc = b1[t];
#pragma unroll 8
  for (int kk = 0; kk < 512; ++kk) acc = fmaf(ecat[kk], w1[kk * 256 + t], acc);
  h[t] = fmaxf(acc, 0.f);
  __syncthreads();
  float a2 = b2[t];
#pragma unroll 8
  for (int kk = 0; kk < 256; ++kk) a2 = fmaf(h[kk], w2[kk * 256 + t], a2);
  eout[r * 256 + t] = a2;
  eb[r * 256 + t] = f2b(a2);
}

// ---------------------------------------------------------------------------
// g2: per row of dots2 [65536,1024]: softmax, top-ke mask, write H.
// One wave per row, 16 f32/lane, 32-step binary search on f32 monotone key.
// ---------------------------------------------------------------------------
__global__ __launch_bounds__(256)
void g2_kernel(const float* __restrict__ d2, const int* __restrict__ kep,
               float* __restrict__ H) {
  const int lane = threadIdx.x & 63, wid = threadIdx.x >> 6;
  const long row = (long)blockIdx.x * 4 + wid;
  const int ke = *kep;
  const float4* src = reinterpret_cast<const float4*>(d2 + row * 1024);
  float4 q0 = src[lane], q1 = src[64 + lane], q2v = src[128 + lane], q3 = src[192 + lane];
  float x[16] = {q0.x, q0.y, q0.z, q0.w, q1.x, q1.y, q1.z, q1.w,
                 q2v.x, q2v.y, q2v.z, q2v.w, q3.x, q3.y, q3.z, q3.w};
  float mx = x[0];
#pragma unroll
  for (int i = 1; i < 16; i++) mx = fmaxf(mx, x[i]);
  for (int sh = 1; sh < 64; sh <<= 1) mx = fmaxf(mx, __shfl_xor(mx, sh));
  float p[16];
  float se = 0.f;
#pragma unroll
  for (int i = 0; i < 16; i++) { p[i] = expf(x[i] - mx); se += p[i]; }
  for (int sh = 1; sh < 64; sh <<= 1) se += __shfl_xor(se, sh);
  const float invs = 1.f / se;
  u32 key[16];
#pragma unroll
  for (int i = 0; i < 16; i++) {
    u32 u = __builtin_bit_cast(u32, x[i]);
    key[i] = u ^ ((u >> 31) ? 0xFFFFFFFFu : 0x80000000u);
  }
  u32 lo = 0;
  for (int b = 31; b >= 0; --b) {
    u32 t = lo | (1u << b);
    int cnt = 0;
#pragma unroll
    for (int i = 0; i < 16; i++) cnt += (key[i] >= t);
    for (int sh = 1; sh < 64; sh <<= 1) cnt += __shfl_xor(cnt, sh);
    if (cnt >= ke) lo = t;
  }
  float4 o0, o1, o2, o3;
  o0.x = key[0] >= lo ? p[0] * invs : 0.f;
  o0.y = key[1] >= lo ? p[1] * invs : 0.f;
  o0.z = key[2] >= lo ? p[2] * invs : 0.f;
  o0.w = key[3] >= lo ? p[3] * invs : 0.f;
  o1.x = key[4] >= lo ? p[4] * invs : 0.f;
  o1.y = key[5] >= lo ? p[5] * invs : 0.f;
  o1.z = key[6] >= lo ? p[6] * invs : 0.f;
  o1.w = key[7] >= lo ? p[7] * invs : 0.f;
  o2.x = key[8] >= lo ? p[8] * invs : 0.f;
  o2.y = key[9] >= lo ? p[9] * invs : 0.f;
  o2.z = key[10] >= lo ? p[10] * invs : 0.f;
  o2.w = key[11] >= lo ? p[11] * invs : 0.f;
  o3.x = key[12] >= lo ? p[12] * invs : 0.f;
  o3.y = key[13] >= lo ? p[13] * invs : 0.f;
  o3.z = key[14] >= lo ? p[14] * invs : 0.f;
  o3.w = key[15] >= lo ? p[15] * invs : 0.f;
  float4* dst = reinterpret_cast<float4*>(H + row * 1024);
  dst[lane] = o0;
  dst[64 + lane] = o1;
  dst[128 + lane] = o2;
  dst[192 + lane] = o3;
}

// ---------------------------------------------------------------------------
extern "C" void kernel_launch(void* const* d_in, const int* in_sizes, int n_in,
                              void* d_out, int out_size, void* d_ws, size_t ws_size,
                              hipStream_t stream) {
  (void)in_sizes; (void)n_in; (void)out_size; (void)d_ws; (void)ws_size;

  float* out = (float*)d_out;
  float* out_edges = out;                       // [1024,256]
  float* out_H = out + NSL * DD;                // [65536,1024]
  float* out_d2 = out_H + NN * NSL;             // [65536,1024]

  // scratch carved from d_out (regions are dead until their writer runs):
  // H region: dots bf16 (134MB) + q2 bf16 (32MB) + small block; overwritten by g2 last.
  char* Hb = (char*)out_H;
  u16* dots = (u16*)Hb;                          // 1024*65536*2
  u16* q2b = (u16*)(Hb + 134217728L);            // 65536*256*2
  char* smb = Hb + 167772160L;
  u16* wcat = (u16*)smb;      smb += 768 * 256 * 2;
  float* bcat = (float*)smb;  smb += 768 * 4;
  float* e_f = (float*)smb;   smb += 1024 * 256 * 4;
  u16* e_b = (u16*)smb;       smb += 1024 * 256 * 2;
  u16* q_b = (u16*)smb;       smb += 1024 * 256 * 2;
  float* updf = (float*)smb;  smb += 1024 * 256 * 4;
  u16* edg_b = (u16*)smb;     smb += 1024 * 256 * 2;
  u16* k2_b = (u16*)smb;      smb += 1024 * 256 * 2;
  // dots2 region: x_ln, k, v bf16 (32MB each); overwritten by gemm<3>.
  char* Db = (char*)out_d2;
  u16* xln = (u16*)Db;
  u16* kb_ = (u16*)(Db + 33554432L);
  u16* vb_ = (u16*)(Db + 67108864L);

  hipFuncSetAttribute(reinterpret_cast<const void*>(d2d3_kernel),
                      hipFuncAttributeMaxDynamicSharedMemorySize,
                      (int)sizeof(D3Shm));

  prep_w_kernel<<<768, 256, 0, stream>>>(
      (const float*)d_in[4], (const float*)d_in[6], (const float*)d_in[8],
      (const float*)d_in[5], (const float*)d_in[7], (const float*)d_in[9], wcat, bcat);
  edges_e_kernel<<<256, 256, 0, stream>>>(
      (const float*)d_in[1], (const float*)d_in[2], (const float*)d_in[3],
      (const float*)d_in[16], (const float*)d_in[17], e_f, e_b);
  ln_x_kernel<<<16384, 256, 0, stream>>>(
      (const float*)d_in[0], (const float*)d_in[14], (const float*)d_in[15], xln);
  gemm_bt<1><<<dim3(2, 8), 256, 0, stream>>>(e_b, wcat + 512 * 256, bcat + 512, 1.f,
                                             q_b, nullptr, nullptr, nullptr);
  gemm_bt<0><<<dim3(6, 512), 256, 0, stream>>>(xln, wcat, bcat, 1.f,
                                               kb_, vb_, q2b, nullptr);
  gemm_bt<2><<<dim3(512, 8), 256, 0, stream>>>(q_b, kb_, nullptr, 0.0625f,
                                               dots, nullptr, nullptr, nullptr);
  d2d3_kernel<<<1024, 1024, sizeof(D3Shm), stream>>>(dots, vb_, (const int*)d_in[18], updf);
  mlp_kernel<<<1024, 256, 0, stream>>>(e_f, updf,
                                       (const float*)d_in[10], (const float*)d_in[11],
                                       (const float*)d_in[12], (const float*)d_in[13],
                                       out_edges, edg_b);
  gemm_bt<1><<<dim3(2, 8), 256, 0, stream>>>(edg_b, wcat, bcat, 1.f,
                                             k2_b, nullptr, nullptr, nullptr);
  gemm_bt<3><<<dim3(8, 512), 256, 0, stream>>>(q2b, k2_b, nullptr, 0.0625f,
                                               nullptr, nullptr, nullptr, out_d2);
  g2_kernel<<<16384, 256, 0, stream>>>(out_d2, (const int*)d_in[19], out_H);
}